// Round 1
// baseline (179.056 us; speedup 1.0000x reference)
//
#include <hip/hip_runtime.h>
#include <hip/hip_bf16.h>
#include <math.h>

#define BB 8
#define NN 2048
#define HH 768
#define D1 128
#define D2 64
#define BN (BB*NN)            // 16384 rows total
#define NCH 16                // split-n chunks for S1/S2 partial reductions
#define ROWS_PER_CH (NN/NCH)  // 128

// workspace offsets (floats)
#define OFF_H   0u            // [BN][128]
#define OFF_XN  2097152u      // [BN][128]
#define OFF_H1  4194304u      // [BN][64]
#define OFF_P1  5242880u      // [8][NCH][128][128]
#define OFF_S1  7340032u      // [8][128][128]
#define OFF_M1  7471104u      // [8][128][64]
#define OFF_R1  7536640u      // [128][64]
#define OFF_P2  7544832u      // [8][NCH][128][64]
#define OFF_S2  8593408u      // [8][128][64]
#define OFF_M2  8658944u      // [8][128]
#define OFF_R2  8659968u      // [64]

// ---------------- K1: h = x @ w1^T + b1  ([16384,768]x[768,128]) ----------------
__global__ __launch_bounds__(256) void k_gemm_h(const float* __restrict__ x,
                                                const float* __restrict__ w1,
                                                const float* __restrict__ b1,
                                                float* __restrict__ h) {
  __shared__ float xs[32][33];
  __shared__ float ws[32][132];
  const int t = threadIdx.x;
  const int tx = t & 31;        // cols tx*4..+3
  const int ty = t >> 5;        // rows ty*4..+3
  const int row0 = blockIdx.x * 32;
  float acc[4][4] = {};
  for (int k0 = 0; k0 < HH; k0 += 32) {
    {
      int r = t >> 3, ks = (t & 7) * 4;
      float4 v = *reinterpret_cast<const float4*>(&x[(size_t)(row0 + r) * HH + k0 + ks]);
      xs[r][ks + 0] = v.x; xs[r][ks + 1] = v.y; xs[r][ks + 2] = v.z; xs[r][ks + 3] = v.w;
    }
#pragma unroll
    for (int l = 0; l < 4; ++l) {
      int idx = l * 256 + t;
      int c = idx >> 3, ks = (idx & 7) * 4;
      float4 v = *reinterpret_cast<const float4*>(&w1[(size_t)c * HH + k0 + ks]);
      ws[ks + 0][c] = v.x; ws[ks + 1][c] = v.y; ws[ks + 2][c] = v.z; ws[ks + 3][c] = v.w;
    }
    __syncthreads();
#pragma unroll
    for (int kk = 0; kk < 32; ++kk) {
      float a[4], b[4];
#pragma unroll
      for (int i = 0; i < 4; ++i) a[i] = xs[ty * 4 + i][kk];
#pragma unroll
      for (int j = 0; j < 4; ++j) b[j] = ws[kk][tx * 4 + j];
#pragma unroll
      for (int i = 0; i < 4; ++i)
#pragma unroll
        for (int j = 0; j < 4; ++j) acc[i][j] += a[i] * b[j];
    }
    __syncthreads();
  }
#pragma unroll
  for (int i = 0; i < 4; ++i) {
    int r = row0 + ty * 4 + i;
    float4 v = make_float4(acc[i][0] + b1[tx * 4 + 0], acc[i][1] + b1[tx * 4 + 1],
                           acc[i][2] + b1[tx * 4 + 2], acc[i][3] + b1[tx * 4 + 3]);
    *reinterpret_cast<float4*>(&h[(size_t)r * D1 + tx * 4]) = v;
  }
}

// ---------------- K2: row-normalize -> xn ----------------
__global__ __launch_bounds__(256) void k_norm(const float* __restrict__ h, float* __restrict__ xn) {
  int row = blockIdx.x * 4 + (threadIdx.x >> 6);
  int lane = threadIdx.x & 63;
  const float* hr = h + (size_t)row * D1;
  float v0 = hr[lane], v1 = hr[lane + 64];
  float s = v0 * v0 + v1 * v1;
#pragma unroll
  for (int m = 1; m < 64; m <<= 1) s += __shfl_xor(s, m, 64);
  float inv = 1.0f / fmaxf(sqrtf(s), 1e-8f);
  xn[(size_t)row * D1 + lane] = v0 * inv;
  xn[(size_t)row * D1 + lane + 64] = v1 * inv;
}

// ---------------- K3a: per-chunk partials of S1 = xn^T @ h  ([128][128] per b) ----------------
__global__ __launch_bounds__(256) void k_s1_partial(const float* __restrict__ xn,
                                                    const float* __restrict__ h,
                                                    float* __restrict__ P1) {
  __shared__ float xs[8][128];
  __shared__ float hs[8][128];
  const int t = threadIdx.x;
  const int ch = blockIdx.x, b = blockIdx.y;
  const int ty = t >> 4, tx = t & 15;   // d rows ty*8..+7 ; e cols tx*8..+7
  float acc[8][8] = {};
  const size_t base = ((size_t)b * NN + ch * ROWS_PER_CH) * D1;
  for (int s8 = 0; s8 < ROWS_PER_CH / 8; ++s8) {
    int r = t >> 5, c4 = (t & 31) * 4;
    *reinterpret_cast<float4*>(&xs[r][c4]) =
        *reinterpret_cast<const float4*>(&xn[base + (size_t)(s8 * 8 + r) * D1 + c4]);
    *reinterpret_cast<float4*>(&hs[r][c4]) =
        *reinterpret_cast<const float4*>(&h[base + (size_t)(s8 * 8 + r) * D1 + c4]);
    __syncthreads();
#pragma unroll
    for (int nn = 0; nn < 8; ++nn) {
      float a[8], bb[8];
#pragma unroll
      for (int i = 0; i < 8; ++i) a[i] = xs[nn][ty * 8 + i];
#pragma unroll
      for (int j = 0; j < 8; ++j) bb[j] = hs[nn][tx * 8 + j];
#pragma unroll
      for (int i = 0; i < 8; ++i)
#pragma unroll
        for (int j = 0; j < 8; ++j) acc[i][j] += a[i] * bb[j];
    }
    __syncthreads();
  }
  float* P = P1 + ((size_t)b * NCH + ch) * (D1 * D1);
#pragma unroll
  for (int i = 0; i < 8; ++i)
#pragma unroll
    for (int j4 = 0; j4 < 2; ++j4) {
      float4 v = make_float4(acc[i][j4 * 4 + 0], acc[i][j4 * 4 + 1],
                             acc[i][j4 * 4 + 2], acc[i][j4 * 4 + 3]);
      *reinterpret_cast<float4*>(&P[(size_t)(ty * 8 + i) * D1 + tx * 8 + j4 * 4]) = v;
    }
}

// ---------------- generic chunk reduce: S[b][idx] = sum_c P[b][c][idx] ----------------
__global__ __launch_bounds__(256) void k_reduce(const float* __restrict__ P, float* __restrict__ S, int len) {
  int b = blockIdx.y;
  int idx = blockIdx.x * 256 + threadIdx.x;
  if (idx >= len) return;
  const float* p = P + (size_t)b * NCH * len + idx;
  float s = 0.f;
#pragma unroll
  for (int c = 0; c < NCH; ++c) s += p[(size_t)c * len];
  S[(size_t)b * len + idx] = s;
}

// ---------------- K4: M1 = S1 @ c1_lw^T / 2047 ; R1 = c1_rw^T - c1_lw^T/2047 ----------------
__global__ __launch_bounds__(256) void k_m1r1(const float* __restrict__ S1,
                                              const float* __restrict__ c1_lw,
                                              const float* __restrict__ c1_rw,
                                              float* __restrict__ M1, float* __restrict__ R1) {
  const int chunk = blockIdx.x, b = blockIdx.y, t = threadIdx.x;
  const float inv = 1.0f / 2047.0f;
  for (int i = chunk * 2048 + t; i < (chunk + 1) * 2048; i += 256) {
    int d = i >> 6, o = i & 63;
    const float* srow = S1 + (size_t)b * D1 * D1 + (size_t)d * D1;
    const float* wrow = c1_lw + (size_t)o * D1;
    float4 s4 = make_float4(0.f, 0.f, 0.f, 0.f);
    for (int e = 0; e < D1; e += 4) {
      float4 a = *reinterpret_cast<const float4*>(&srow[e]);
      float4 w = *reinterpret_cast<const float4*>(&wrow[e]);
      s4.x += a.x * w.x; s4.y += a.y * w.y; s4.z += a.z * w.z; s4.w += a.w * w.w;
    }
    M1[(size_t)b * D1 * D2 + i] = (s4.x + s4.y + s4.z + s4.w) * inv;
    if (b == 0) R1[i] = c1_rw[(size_t)o * D1 + d] - c1_lw[(size_t)o * D1 + d] * inv;
  }
}

// ---------------- K5: h1 = relu(xn@M1 + h@R1 + c1_lb) ----------------
__global__ __launch_bounds__(256) void k_h1(const float* __restrict__ xn, const float* __restrict__ h,
                                            const float* __restrict__ M1, const float* __restrict__ R1,
                                            const float* __restrict__ c1_lb, float* __restrict__ h1) {
  __shared__ float xs[64][17], hsh[64][17], Ms[16][D2], Rs[16][D2];
  const int t = threadIdx.x;
  const int row0 = blockIdx.x * 64;
  const int b = row0 >> 11;
  const int ty = t >> 4, tx = t & 15;   // rows ty*4..+3 ; cols tx*4..+3
  float acc[4][4] = {};
  for (int k0 = 0; k0 < D1; k0 += 16) {
    {
      int r = t >> 2, ks = (t & 3) * 4;
      float4 v = *reinterpret_cast<const float4*>(&xn[(size_t)(row0 + r) * D1 + k0 + ks]);
      xs[r][ks] = v.x; xs[r][ks + 1] = v.y; xs[r][ks + 2] = v.z; xs[r][ks + 3] = v.w;
      float4 u = *reinterpret_cast<const float4*>(&h[(size_t)(row0 + r) * D1 + k0 + ks]);
      hsh[r][ks] = u.x; hsh[r][ks + 1] = u.y; hsh[r][ks + 2] = u.z; hsh[r][ks + 3] = u.w;
      int kk = t >> 4, o4 = (t & 15) * 4;
      *reinterpret_cast<float4*>(&Ms[kk][o4]) =
          *reinterpret_cast<const float4*>(&M1[(size_t)b * D1 * D2 + (size_t)(k0 + kk) * D2 + o4]);
      *reinterpret_cast<float4*>(&Rs[kk][o4]) =
          *reinterpret_cast<const float4*>(&R1[(size_t)(k0 + kk) * D2 + o4]);
    }
    __syncthreads();
#pragma unroll
    for (int kk = 0; kk < 16; ++kk) {
      float a[4], c[4], bm[4], br[4];
#pragma unroll
      for (int i = 0; i < 4; ++i) { a[i] = xs[ty * 4 + i][kk]; c[i] = hsh[ty * 4 + i][kk]; }
#pragma unroll
      for (int j = 0; j < 4; ++j) { bm[j] = Ms[kk][tx * 4 + j]; br[j] = Rs[kk][tx * 4 + j]; }
#pragma unroll
      for (int i = 0; i < 4; ++i)
#pragma unroll
        for (int j = 0; j < 4; ++j) acc[i][j] += a[i] * bm[j] + c[i] * br[j];
    }
    __syncthreads();
  }
#pragma unroll
  for (int i = 0; i < 4; ++i) {
    int r = row0 + ty * 4 + i;
#pragma unroll
    for (int j = 0; j < 4; ++j) {
      float v = acc[i][j] + c1_lb[tx * 4 + j];
      h1[(size_t)r * D2 + tx * 4 + j] = fmaxf(v, 0.0f);
    }
  }
}

// ---------------- K6a: per-chunk partials of S2 = xn^T @ h1 ([128][64] per b) ----------------
__global__ __launch_bounds__(256) void k_s2_partial(const float* __restrict__ xn,
                                                    const float* __restrict__ h1,
                                                    float* __restrict__ P2) {
  __shared__ float xs[8][128];
  __shared__ float hs[8][64];
  const int t = threadIdx.x;
  const int ch = blockIdx.x, b = blockIdx.y;
  const int ty = t >> 3, tx = t & 7;   // d rows ty*4..+3 ; o cols tx*8..+7
  float acc[4][8] = {};
  const size_t xbase = ((size_t)b * NN + ch * ROWS_PER_CH) * D1;
  const size_t hbase = ((size_t)b * NN + ch * ROWS_PER_CH) * D2;
  for (int s8 = 0; s8 < ROWS_PER_CH / 8; ++s8) {
    int r = t >> 5, c4 = (t & 31) * 4;
    *reinterpret_cast<float4*>(&xs[r][c4]) =
        *reinterpret_cast<const float4*>(&xn[xbase + (size_t)(s8 * 8 + r) * D1 + c4]);
    if (t < 128) {
      int r2 = t >> 4, c42 = (t & 15) * 4;
      *reinterpret_cast<float4*>(&hs[r2][c42]) =
          *reinterpret_cast<const float4*>(&h1[hbase + (size_t)(s8 * 8 + r2) * D2 + c42]);
    }
    __syncthreads();
#pragma unroll
    for (int nn = 0; nn < 8; ++nn) {
      float a[4], bb[8];
#pragma unroll
      for (int i = 0; i < 4; ++i) a[i] = xs[nn][ty * 4 + i];
#pragma unroll
      for (int j = 0; j < 8; ++j) bb[j] = hs[nn][tx * 8 + j];
#pragma unroll
      for (int i = 0; i < 4; ++i)
#pragma unroll
        for (int j = 0; j < 8; ++j) acc[i][j] += a[i] * bb[j];
    }
    __syncthreads();
  }
  float* P = P2 + ((size_t)b * NCH + ch) * (D1 * D2);
#pragma unroll
  for (int i = 0; i < 4; ++i)
#pragma unroll
    for (int j4 = 0; j4 < 2; ++j4) {
      float4 v = make_float4(acc[i][j4 * 4 + 0], acc[i][j4 * 4 + 1],
                             acc[i][j4 * 4 + 2], acc[i][j4 * 4 + 3]);
      *reinterpret_cast<float4*>(&P[(size_t)(ty * 4 + i) * D2 + tx * 8 + j4 * 4]) = v;
    }
}

// ---------------- K7: m2 = S2 @ c2_lw / 2047 ; r2 = c2_rw - c2_lw/2047 ----------------
__global__ __launch_bounds__(128) void k_m2r2(const float* __restrict__ S2,
                                              const float* __restrict__ c2_lw,
                                              const float* __restrict__ c2_rw,
                                              float* __restrict__ m2, float* __restrict__ r2) {
  const int b = blockIdx.x, d = threadIdx.x;
  const float inv = 1.0f / 2047.0f;
  const float* srow = S2 + (size_t)b * D1 * D2 + (size_t)d * D2;
  float s = 0.f;
  for (int o = 0; o < D2; ++o) s += srow[o] * c2_lw[o];
  m2[b * D1 + d] = s * inv;
  if (b == 0 && d < D2) r2[d] = c2_rw[d] - c2_lw[d] * inv;
}

// ---------------- K8: out = sigmoid(xn.m2 + h1.r2 + c2_lb) * mask ----------------
__global__ __launch_bounds__(256) void k_out(const float* __restrict__ xn, const float* __restrict__ h1,
                                             const float* __restrict__ m2, const float* __restrict__ r2,
                                             const float* __restrict__ c2_lb, const float* __restrict__ mask,
                                             float* __restrict__ out) {
  int row = blockIdx.x * 4 + (threadIdx.x >> 6);
  int lane = threadIdx.x & 63;
  int b = row >> 11;
  float s = xn[(size_t)row * D1 + lane] * m2[b * D1 + lane]
          + xn[(size_t)row * D1 + 64 + lane] * m2[b * D1 + 64 + lane]
          + h1[(size_t)row * D2 + lane] * r2[lane];
#pragma unroll
  for (int m = 1; m < 64; m <<= 1) s += __shfl_xor(s, m, 64);
  if (lane == 0) {
    float v = s + c2_lb[0];
    out[row] = (1.0f / (1.0f + expf(-v))) * mask[row];
  }
}

extern "C" void kernel_launch(void* const* d_in, const int* in_sizes, int n_in,
                              void* d_out, int out_size, void* d_ws, size_t ws_size,
                              hipStream_t stream) {
  const float* x      = (const float*)d_in[0];
  const float* mask   = (const float*)d_in[1];
  const float* w1     = (const float*)d_in[2];
  const float* b1     = (const float*)d_in[3];
  const float* c1_lw  = (const float*)d_in[4];
  const float* c1_lb  = (const float*)d_in[5];
  const float* c1_rw  = (const float*)d_in[6];
  const float* c2_lw  = (const float*)d_in[7];
  const float* c2_lb  = (const float*)d_in[8];
  const float* c2_rw  = (const float*)d_in[9];
  float* ws  = (float*)d_ws;
  float* h   = ws + OFF_H;
  float* xn  = ws + OFF_XN;
  float* h1  = ws + OFF_H1;
  float* P1  = ws + OFF_P1;
  float* S1  = ws + OFF_S1;
  float* M1  = ws + OFF_M1;
  float* R1  = ws + OFF_R1;
  float* P2  = ws + OFF_P2;
  float* S2  = ws + OFF_S2;
  float* m2  = ws + OFF_M2;
  float* r2  = ws + OFF_R2;
  float* out = (float*)d_out;

  k_gemm_h<<<dim3(BN / 32), dim3(256), 0, stream>>>(x, w1, b1, h);
  k_norm<<<dim3(BN / 4), dim3(256), 0, stream>>>(h, xn);
  k_s1_partial<<<dim3(NCH, BB), dim3(256), 0, stream>>>(xn, h, P1);
  k_reduce<<<dim3(64, BB), dim3(256), 0, stream>>>(P1, S1, D1 * D1);
  k_m1r1<<<dim3(4, BB), dim3(256), 0, stream>>>(S1, c1_lw, c1_rw, M1, R1);
  k_h1<<<dim3(BN / 64), dim3(256), 0, stream>>>(xn, h, M1, R1, c1_lb, h1);
  k_s2_partial<<<dim3(NCH, BB), dim3(256), 0, stream>>>(xn, h1, P2);
  k_reduce<<<dim3(32, BB), dim3(256), 0, stream>>>(P2, S2, D1 * D2);
  k_m2r2<<<dim3(BB), dim3(128), 0, stream>>>(S2, c2_lw, c2_rw, m2, r2);
  k_out<<<dim3(BN / 4), dim3(256), 0, stream>>>(xn, h1, m2, r2, c2_lb, mask, out);
}

// Round 2
// 142.872 us; speedup vs baseline: 1.2533x; 1.2533x over previous
//
#include <hip/hip_runtime.h>
#include <hip/hip_bf16.h>
#include <math.h>

#define BB 8
#define NN 2048
#define HH 768
#define D1 128
#define D2 64
#define BN (BB*NN)            // 16384 rows total
#define NCH 16                // split-n chunks for S1/S2 partial reductions
#define ROWS_PER_CH (NN/NCH)  // 128

// workspace offsets (floats)
#define OFF_H   0u            // [BN][128]
#define OFF_XN  2097152u      // [BN][128]
#define OFF_H1  4194304u      // [BN][64]
#define OFF_P1  5242880u      // [8][NCH][128][128]  (w1b bf16 also lives here pre-S1)
#define OFF_S1  7340032u      // [8][128][128]
#define OFF_M1  7471104u      // [8][128][64]
#define OFF_R1  7536640u      // [128][64]
#define OFF_P2  7544832u      // [8][NCH][128][64]
#define OFF_S2  8593408u      // [8][128][64]
#define OFF_M2  8658944u      // [8][128]
#define OFF_R2  8659968u      // [64]

typedef __attribute__((ext_vector_type(8))) short short8v;
typedef __attribute__((ext_vector_type(4))) float f32x4;

__device__ __forceinline__ unsigned short f2bf(float f) {
  unsigned int u = __builtin_bit_cast(unsigned int, f);
  u = (u + 0x7fffu + ((u >> 16) & 1u)) >> 16;
  return (unsigned short)u;
}

#define GLDS16(gp, lp)                                                        \
  __builtin_amdgcn_global_load_lds((const __attribute__((address_space(1))) void*)(gp), \
                                   (__attribute__((address_space(3))) void*)(lp), 16, 0, 0)

// ---------------- K0: convert w1 (fp32 [128][768]) -> bf16 ----------------
__global__ __launch_bounds__(256) void k_cvt_w1(const float* __restrict__ w1,
                                                unsigned short* __restrict__ w1b) {
  int i = (blockIdx.x * 256 + threadIdx.x) * 4;
  float4 v = *reinterpret_cast<const float4*>(&w1[i]);
  ushort4 o;
  o.x = f2bf(v.x); o.y = f2bf(v.y); o.z = f2bf(v.z); o.w = f2bf(v.w);
  *reinterpret_cast<ushort4*>(&w1b[i]) = o;
}

// ---------------- K1: h = x @ w1^T + b1 via bf16 MFMA, fused row-norm ----------------
// BM=64 rows, BN=128 (all) cols, BK=32, 4 waves (2M x 2N), wave tile 32x64.
__global__ __launch_bounds__(256) void k_gemm_h(const float* __restrict__ x,
                                                const unsigned short* __restrict__ w1b,
                                                const float* __restrict__ b1,
                                                float* __restrict__ h,
                                                float* __restrict__ xn) {
  __shared__ __align__(16) unsigned short As[2][64][32];   // 8 KB
  __shared__ __align__(16) unsigned short Bs[2][128][32];  // 16 KB
  __shared__ float norms[64][2];

  const int t = threadIdx.x;
  const int w = t >> 6;          // wave 0..3
  const int l = t & 63;          // lane
  const int wm = w & 1;          // M-half
  const int wn = w >> 1;         // N-half
  const int row0 = blockIdx.x * 64;

  // A staging mapping: thread t -> row t>>2 (0..63), seg t&3 (8 k-elems each)
  const int arow = t >> 2;
  const int aseg = t & 3;
  const size_t xbase = (size_t)(row0 + arow) * HH;

  f32x4 acc[2][4] = {};

  // ---- prologue: stage buffer 0 (kt = 0, k0 = 0) ----
  {
#pragma unroll
    for (int q = 0; q < 2; ++q) {
      int brow = w * 32 + q * 16 + (l >> 2);
      const unsigned short* gp = w1b + (size_t)brow * HH + (l & 3) * 8;
      GLDS16(gp, &Bs[0][w * 32 + q * 16][0]);
    }
    float4 xa = *reinterpret_cast<const float4*>(&x[xbase + aseg * 8]);
    float4 xb = *reinterpret_cast<const float4*>(&x[xbase + aseg * 8 + 4]);
    short8v v;
    v[0] = (short)f2bf(xa.x); v[1] = (short)f2bf(xa.y);
    v[2] = (short)f2bf(xa.z); v[3] = (short)f2bf(xa.w);
    v[4] = (short)f2bf(xb.x); v[5] = (short)f2bf(xb.y);
    v[6] = (short)f2bf(xb.z); v[7] = (short)f2bf(xb.w);
    *reinterpret_cast<short8v*>(&As[0][arow][aseg * 8]) = v;
  }

  for (int kt = 0; kt < HH / 32; ++kt) {
    const int cur = kt & 1, nxt = cur ^ 1;
    __syncthreads();  // drains vmcnt/lgkm: As[cur]/Bs[cur] ready for everyone

    float4 xa, xb;
    if (kt < HH / 32 - 1) {
      const int k0n = (kt + 1) * 32;
      // issue next B tile direct-to-LDS (stays in flight during compute)
#pragma unroll
      for (int q = 0; q < 2; ++q) {
        int brow = w * 32 + q * 16 + (l >> 2);
        const unsigned short* gp = w1b + (size_t)brow * HH + k0n + (l & 3) * 8;
        GLDS16(gp, &Bs[nxt][w * 32 + q * 16][0]);
      }
      // issue next A tile into regs
      xa = *reinterpret_cast<const float4*>(&x[xbase + k0n + aseg * 8]);
      xb = *reinterpret_cast<const float4*>(&x[xbase + k0n + aseg * 8 + 4]);
    }

    // ---- compute on cur ----
    short8v a[2], b[4];
#pragma unroll
    for (int mi = 0; mi < 2; ++mi)
      a[mi] = *reinterpret_cast<const short8v*>(&As[cur][wm * 32 + mi * 16 + (l & 15)][(l >> 4) * 8]);
#pragma unroll
    for (int ni = 0; ni < 4; ++ni)
      b[ni] = *reinterpret_cast<const short8v*>(&Bs[cur][wn * 64 + ni * 16 + (l & 15)][(l >> 4) * 8]);
#pragma unroll
    for (int mi = 0; mi < 2; ++mi)
#pragma unroll
      for (int ni = 0; ni < 4; ++ni)
        acc[mi][ni] = __builtin_amdgcn_mfma_f32_16x16x32_bf16(a[mi], b[ni], acc[mi][ni], 0, 0, 0);

    if (kt < HH / 32 - 1) {
      short8v v;
      v[0] = (short)f2bf(xa.x); v[1] = (short)f2bf(xa.y);
      v[2] = (short)f2bf(xa.z); v[3] = (short)f2bf(xa.w);
      v[4] = (short)f2bf(xb.x); v[5] = (short)f2bf(xb.y);
      v[6] = (short)f2bf(xb.z); v[7] = (short)f2bf(xb.w);
      *reinterpret_cast<short8v*>(&As[nxt][arow][aseg * 8]) = v;
    }
  }

  // ---- epilogue: bias add, fused row-norm, write h + xn ----
  float bv[4];
#pragma unroll
  for (int ni = 0; ni < 4; ++ni) bv[ni] = b1[wn * 64 + ni * 16 + (l & 15)];
#pragma unroll
  for (int mi = 0; mi < 2; ++mi)
#pragma unroll
    for (int ni = 0; ni < 4; ++ni)
#pragma unroll
      for (int r = 0; r < 4; ++r) acc[mi][ni][r] += bv[ni];

  // per-lane partial sum of squares per row (mi, r), then reduce over 16 lanes
  float ss[2][4];
#pragma unroll
  for (int mi = 0; mi < 2; ++mi)
#pragma unroll
    for (int r = 0; r < 4; ++r) {
      float s = 0.f;
#pragma unroll
      for (int ni = 0; ni < 4; ++ni) { float v = acc[mi][ni][r]; s += v * v; }
#pragma unroll
      for (int m = 1; m < 16; m <<= 1) s += __shfl_xor(s, m, 64);
      ss[mi][r] = s;
    }
  if ((l & 15) == 0) {
#pragma unroll
    for (int mi = 0; mi < 2; ++mi)
#pragma unroll
      for (int r = 0; r < 4; ++r)
        norms[wm * 32 + mi * 16 + (l >> 4) * 4 + r][wn] = ss[mi][r];
  }
  __syncthreads();

#pragma unroll
  for (int mi = 0; mi < 2; ++mi)
#pragma unroll
    for (int r = 0; r < 4; ++r) {
      int row = wm * 32 + mi * 16 + (l >> 4) * 4 + r;
      float tot = norms[row][0] + norms[row][1];
      float inv = 1.0f / fmaxf(sqrtf(tot), 1e-8f);
      size_t gbase = (size_t)(row0 + row) * D1;
#pragma unroll
      for (int ni = 0; ni < 4; ++ni) {
        int col = wn * 64 + ni * 16 + (l & 15);
        float v = acc[mi][ni][r];
        h[gbase + col] = v;
        xn[gbase + col] = v * inv;
      }
    }
}

// ---------------- K3a: per-chunk partials of S1 = xn^T @ h  ([128][128] per b) ----------------
__global__ __launch_bounds__(256) void k_s1_partial(const float* __restrict__ xn,
                                                    const float* __restrict__ h,
                                                    float* __restrict__ P1) {
  __shared__ float xs[8][128];
  __shared__ float hs[8][128];
  const int t = threadIdx.x;
  const int ch = blockIdx.x, b = blockIdx.y;
  const int ty = t >> 4, tx = t & 15;   // d rows ty*8..+7 ; e cols tx*8..+7
  float acc[8][8] = {};
  const size_t base = ((size_t)b * NN + ch * ROWS_PER_CH) * D1;
  for (int s8 = 0; s8 < ROWS_PER_CH / 8; ++s8) {
    int r = t >> 5, c4 = (t & 31) * 4;
    *reinterpret_cast<float4*>(&xs[r][c4]) =
        *reinterpret_cast<const float4*>(&xn[base + (size_t)(s8 * 8 + r) * D1 + c4]);
    *reinterpret_cast<float4*>(&hs[r][c4]) =
        *reinterpret_cast<const float4*>(&h[base + (size_t)(s8 * 8 + r) * D1 + c4]);
    __syncthreads();
#pragma unroll
    for (int nn = 0; nn < 8; ++nn) {
      float a[8], bb[8];
#pragma unroll
      for (int i = 0; i < 8; ++i) a[i] = xs[nn][ty * 8 + i];
#pragma unroll
      for (int j = 0; j < 8; ++j) bb[j] = hs[nn][tx * 8 + j];
#pragma unroll
      for (int i = 0; i < 8; ++i)
#pragma unroll
        for (int j = 0; j < 8; ++j) acc[i][j] += a[i] * bb[j];
    }
    __syncthreads();
  }
  float* P = P1 + ((size_t)b * NCH + ch) * (D1 * D1);
#pragma unroll
  for (int i = 0; i < 8; ++i)
#pragma unroll
    for (int j4 = 0; j4 < 2; ++j4) {
      float4 v = make_float4(acc[i][j4 * 4 + 0], acc[i][j4 * 4 + 1],
                             acc[i][j4 * 4 + 2], acc[i][j4 * 4 + 3]);
      *reinterpret_cast<float4*>(&P[(size_t)(ty * 8 + i) * D1 + tx * 8 + j4 * 4]) = v;
    }
}

// ---------------- generic chunk reduce: S[b][idx] = sum_c P[b][c][idx] ----------------
__global__ __launch_bounds__(256) void k_reduce(const float* __restrict__ P, float* __restrict__ S, int len) {
  int b = blockIdx.y;
  int idx = blockIdx.x * 256 + threadIdx.x;
  if (idx >= len) return;
  const float* p = P + (size_t)b * NCH * len + idx;
  float s = 0.f;
#pragma unroll
  for (int c = 0; c < NCH; ++c) s += p[(size_t)c * len];
  S[(size_t)b * len + idx] = s;
}

// ---------------- K4: M1 = S1 @ c1_lw^T / 2047 ; R1 = c1_rw^T - c1_lw^T/2047 ----------------
__global__ __launch_bounds__(256) void k_m1r1(const float* __restrict__ S1,
                                              const float* __restrict__ c1_lw,
                                              const float* __restrict__ c1_rw,
                                              float* __restrict__ M1, float* __restrict__ R1) {
  const int chunk = blockIdx.x, b = blockIdx.y, t = threadIdx.x;
  const float inv = 1.0f / 2047.0f;
  for (int i = chunk * 2048 + t; i < (chunk + 1) * 2048; i += 256) {
    int d = i >> 6, o = i & 63;
    const float* srow = S1 + (size_t)b * D1 * D1 + (size_t)d * D1;
    const float* wrow = c1_lw + (size_t)o * D1;
    float4 s4 = make_float4(0.f, 0.f, 0.f, 0.f);
    for (int e = 0; e < D1; e += 4) {
      float4 a = *reinterpret_cast<const float4*>(&srow[e]);
      float4 w = *reinterpret_cast<const float4*>(&wrow[e]);
      s4.x += a.x * w.x; s4.y += a.y * w.y; s4.z += a.z * w.z; s4.w += a.w * w.w;
    }
    M1[(size_t)b * D1 * D2 + i] = (s4.x + s4.y + s4.z + s4.w) * inv;
    if (b == 0) R1[i] = c1_rw[(size_t)o * D1 + d] - c1_lw[(size_t)o * D1 + d] * inv;
  }
}

// ---------------- K5: h1 = relu(xn@M1 + h@R1 + c1_lb) ----------------
__global__ __launch_bounds__(256) void k_h1(const float* __restrict__ xn, const float* __restrict__ h,
                                            const float* __restrict__ M1, const float* __restrict__ R1,
                                            const float* __restrict__ c1_lb, float* __restrict__ h1) {
  __shared__ float xs[64][17], hsh[64][17], Ms[16][D2], Rs[16][D2];
  const int t = threadIdx.x;
  const int row0 = blockIdx.x * 64;
  const int b = row0 >> 11;
  const int ty = t >> 4, tx = t & 15;   // rows ty*4..+3 ; cols tx*4..+3
  float acc[4][4] = {};
  for (int k0 = 0; k0 < D1; k0 += 16) {
    {
      int r = t >> 2, ks = (t & 3) * 4;
      float4 v = *reinterpret_cast<const float4*>(&xn[(size_t)(row0 + r) * D1 + k0 + ks]);
      xs[r][ks] = v.x; xs[r][ks + 1] = v.y; xs[r][ks + 2] = v.z; xs[r][ks + 3] = v.w;
      float4 u = *reinterpret_cast<const float4*>(&h[(size_t)(row0 + r) * D1 + k0 + ks]);
      hsh[r][ks] = u.x; hsh[r][ks + 1] = u.y; hsh[r][ks + 2] = u.z; hsh[r][ks + 3] = u.w;
      int kk = t >> 4, o4 = (t & 15) * 4;
      *reinterpret_cast<float4*>(&Ms[kk][o4]) =
          *reinterpret_cast<const float4*>(&M1[(size_t)b * D1 * D2 + (size_t)(k0 + kk) * D2 + o4]);
      *reinterpret_cast<float4*>(&Rs[kk][o4]) =
          *reinterpret_cast<const float4*>(&R1[(size_t)(k0 + kk) * D2 + o4]);
    }
    __syncthreads();
#pragma unroll
    for (int kk = 0; kk < 16; ++kk) {
      float a[4], c[4], bm[4], br[4];
#pragma unroll
      for (int i = 0; i < 4; ++i) { a[i] = xs[ty * 4 + i][kk]; c[i] = hsh[ty * 4 + i][kk]; }
#pragma unroll
      for (int j = 0; j < 4; ++j) { bm[j] = Ms[kk][tx * 4 + j]; br[j] = Rs[kk][tx * 4 + j]; }
#pragma unroll
      for (int i = 0; i < 4; ++i)
#pragma unroll
        for (int j = 0; j < 4; ++j) acc[i][j] += a[i] * bm[j] + c[i] * br[j];
    }
    __syncthreads();
  }
#pragma unroll
  for (int i = 0; i < 4; ++i) {
    int r = row0 + ty * 4 + i;
#pragma unroll
    for (int j = 0; j < 4; ++j) {
      float v = acc[i][j] + c1_lb[tx * 4 + j];
      h1[(size_t)r * D2 + tx * 4 + j] = fmaxf(v, 0.0f);
    }
  }
}

// ---------------- K6a: per-chunk partials of S2 = xn^T @ h1 ([128][64] per b) ----------------
__global__ __launch_bounds__(256) void k_s2_partial(const float* __restrict__ xn,
                                                    const float* __restrict__ h1,
                                                    float* __restrict__ P2) {
  __shared__ float xs[8][128];
  __shared__ float hs[8][64];
  const int t = threadIdx.x;
  const int ch = blockIdx.x, b = blockIdx.y;
  const int ty = t >> 3, tx = t & 7;   // d rows ty*4..+3 ; o cols tx*8..+7
  float acc[4][8] = {};
  const size_t xbase = ((size_t)b * NN + ch * ROWS_PER_CH) * D1;
  const size_t hbase = ((size_t)b * NN + ch * ROWS_PER_CH) * D2;
  for (int s8 = 0; s8 < ROWS_PER_CH / 8; ++s8) {
    int r = t >> 5, c4 = (t & 31) * 4;
    *reinterpret_cast<float4*>(&xs[r][c4]) =
        *reinterpret_cast<const float4*>(&xn[xbase + (size_t)(s8 * 8 + r) * D1 + c4]);
    if (t < 128) {
      int r2 = t >> 4, c42 = (t & 15) * 4;
      *reinterpret_cast<float4*>(&hs[r2][c42]) =
          *reinterpret_cast<const float4*>(&h1[hbase + (size_t)(s8 * 8 + r2) * D2 + c42]);
    }
    __syncthreads();
#pragma unroll
    for (int nn = 0; nn < 8; ++nn) {
      float a[4], bb[8];
#pragma unroll
      for (int i = 0; i < 4; ++i) a[i] = xs[nn][ty * 4 + i];
#pragma unroll
      for (int j = 0; j < 8; ++j) bb[j] = hs[nn][tx * 8 + j];
#pragma unroll
      for (int i = 0; i < 4; ++i)
#pragma unroll
        for (int j = 0; j < 8; ++j) acc[i][j] += a[i] * bb[j];
    }
    __syncthreads();
  }
  float* P = P2 + ((size_t)b * NCH + ch) * (D1 * D2);
#pragma unroll
  for (int i = 0; i < 4; ++i)
#pragma unroll
    for (int j4 = 0; j4 < 2; ++j4) {
      float4 v = make_float4(acc[i][j4 * 4 + 0], acc[i][j4 * 4 + 1],
                             acc[i][j4 * 4 + 2], acc[i][j4 * 4 + 3]);
      *reinterpret_cast<float4*>(&P[(size_t)(ty * 4 + i) * D2 + tx * 8 + j4 * 4]) = v;
    }
}

// ---------------- K7: m2 = S2 @ c2_lw / 2047 ; r2 = c2_rw - c2_lw/2047 ----------------
__global__ __launch_bounds__(128) void k_m2r2(const float* __restrict__ S2,
                                              const float* __restrict__ c2_lw,
                                              const float* __restrict__ c2_rw,
                                              float* __restrict__ m2, float* __restrict__ r2) {
  const int b = blockIdx.x, d = threadIdx.x;
  const float inv = 1.0f / 2047.0f;
  const float* srow = S2 + (size_t)b * D1 * D2 + (size_t)d * D2;
  float s = 0.f;
  for (int o = 0; o < D2; ++o) s += srow[o] * c2_lw[o];
  m2[b * D1 + d] = s * inv;
  if (b == 0 && d < D2) r2[d] = c2_rw[d] - c2_lw[d] * inv;
}

// ---------------- K8: out = sigmoid(xn.m2 + h1.r2 + c2_lb) * mask ----------------
__global__ __launch_bounds__(256) void k_out(const float* __restrict__ xn, const float* __restrict__ h1,
                                             const float* __restrict__ m2, const float* __restrict__ r2,
                                             const float* __restrict__ c2_lb, const float* __restrict__ mask,
                                             float* __restrict__ out) {
  int row = blockIdx.x * 4 + (threadIdx.x >> 6);
  int lane = threadIdx.x & 63;
  int b = row >> 11;
  float s = xn[(size_t)row * D1 + lane] * m2[b * D1 + lane]
          + xn[(size_t)row * D1 + 64 + lane] * m2[b * D1 + 64 + lane]
          + h1[(size_t)row * D2 + lane] * r2[lane];
#pragma unroll
  for (int m = 1; m < 64; m <<= 1) s += __shfl_xor(s, m, 64);
  if (lane == 0) {
    float v = s + c2_lb[0];
    out[row] = (1.0f / (1.0f + expf(-v))) * mask[row];
  }
}

extern "C" void kernel_launch(void* const* d_in, const int* in_sizes, int n_in,
                              void* d_out, int out_size, void* d_ws, size_t ws_size,
                              hipStream_t stream) {
  const float* x      = (const float*)d_in[0];
  const float* mask   = (const float*)d_in[1];
  const float* w1     = (const float*)d_in[2];
  const float* b1     = (const float*)d_in[3];
  const float* c1_lw  = (const float*)d_in[4];
  const float* c1_lb  = (const float*)d_in[5];
  const float* c1_rw  = (const float*)d_in[6];
  const float* c2_lw  = (const float*)d_in[7];
  const float* c2_lb  = (const float*)d_in[8];
  const float* c2_rw  = (const float*)d_in[9];
  float* ws  = (float*)d_ws;
  float* h   = ws + OFF_H;
  float* xn  = ws + OFF_XN;
  float* h1  = ws + OFF_H1;
  float* P1  = ws + OFF_P1;
  float* S1  = ws + OFF_S1;
  float* M1  = ws + OFF_M1;
  float* R1  = ws + OFF_R1;
  float* P2  = ws + OFF_P2;
  float* S2  = ws + OFF_S2;
  float* m2  = ws + OFF_M2;
  float* r2  = ws + OFF_R2;
  unsigned short* w1b = (unsigned short*)(ws + OFF_P1);  // reuses P1 region (written later)
  float* out = (float*)d_out;

  k_cvt_w1<<<dim3((D1 * HH) / 1024), dim3(256), 0, stream>>>(w1, w1b);
  k_gemm_h<<<dim3(BN / 64), dim3(256), 0, stream>>>(x, w1b, b1, h, xn);
  k_s1_partial<<<dim3(NCH, BB), dim3(256), 0, stream>>>(xn, h, P1);
  k_reduce<<<dim3(64, BB), dim3(256), 0, stream>>>(P1, S1, D1 * D1);
  k_m1r1<<<dim3(4, BB), dim3(256), 0, stream>>>(S1, c1_lw, c1_rw, M1, R1);
  k_h1<<<dim3(BN / 64), dim3(256), 0, stream>>>(xn, h, M1, R1, c1_lb, h1);
  k_s2_partial<<<dim3(NCH, BB), dim3(256), 0, stream>>>(xn, h1, P2);
  k_reduce<<<dim3(32, BB), dim3(256), 0, stream>>>(P2, S2, D1 * D2);
  k_m2r2<<<dim3(BB), dim3(128), 0, stream>>>(S2, c2_lw, c2_rw, m2, r2);
  k_out<<<dim3(BN / 4), dim3(256), 0, stream>>>(xn, h1, m2, r2, c2_lb, mask, out);
}

// Round 3
// 112.108 us; speedup vs baseline: 1.5972x; 1.2744x over previous
//
#include <hip/hip_runtime.h>
#include <hip/hip_bf16.h>
#include <math.h>

#define BB 8
#define NN 2048
#define HH 768
#define D1 128
#define D2 64
#define BN (BB*NN)            // 16384 rows total
#define NCH 16                // split-n chunks for S1/S2 partial reductions
#define ROWS_PER_CH (NN/NCH)  // 128

// workspace offsets (floats)
#define OFF_H   0u            // [BN][128]
#define OFF_XN  2097152u      // [BN][128]
#define OFF_H1  4194304u      // [BN][64]
#define OFF_P1  5242880u      // [8][NCH][128][128]  (w1b bf16 also lives here pre-S1)
#define OFF_M1  7471104u      // [8][128][64]
#define OFF_R1  7536640u      // [128][64]
#define OFF_P2  7544832u      // [8][NCH][128][64]
#define OFF_M2  8658944u      // [8][128]
#define OFF_R2  8659968u      // [64]

typedef __attribute__((ext_vector_type(8))) short short8v;
typedef __attribute__((ext_vector_type(4))) float f32x4;

__device__ __forceinline__ unsigned short f2bf(float f) {
  unsigned int u = __builtin_bit_cast(unsigned int, f);
  u = (u + 0x7fffu + ((u >> 16) & 1u)) >> 16;
  return (unsigned short)u;
}

#define GLDS16(gp, lp)                                                        \
  __builtin_amdgcn_global_load_lds((const __attribute__((address_space(1))) void*)(gp), \
                                   (__attribute__((address_space(3))) void*)(lp), 16, 0, 0)

// ---------------- K0: convert w1 (fp32 [128][768]) -> bf16 ----------------
__global__ __launch_bounds__(256) void k_cvt_w1(const float* __restrict__ w1,
                                                unsigned short* __restrict__ w1b) {
  int i = (blockIdx.x * 256 + threadIdx.x) * 4;
  float4 v = *reinterpret_cast<const float4*>(&w1[i]);
  ushort4 o;
  o.x = f2bf(v.x); o.y = f2bf(v.y); o.z = f2bf(v.z); o.w = f2bf(v.w);
  *reinterpret_cast<ushort4*>(&w1b[i]) = o;
}

// ---------------- K1: h = x @ w1^T + b1 via bf16 MFMA, fused row-norm ----------------
__global__ __launch_bounds__(256) void k_gemm_h(const float* __restrict__ x,
                                                const unsigned short* __restrict__ w1b,
                                                const float* __restrict__ b1,
                                                float* __restrict__ h,
                                                float* __restrict__ xn) {
  __shared__ __align__(16) unsigned short As[2][64][32];   // 8 KB
  __shared__ __align__(16) unsigned short Bs[2][128][32];  // 16 KB
  __shared__ float norms[64][2];

  const int t = threadIdx.x;
  const int w = t >> 6;          // wave 0..3
  const int l = t & 63;          // lane
  const int wm = w & 1;          // M-half
  const int wn = w >> 1;         // N-half
  const int row0 = blockIdx.x * 64;

  const int arow = t >> 2;
  const int aseg = t & 3;
  const size_t xbase = (size_t)(row0 + arow) * HH;

  f32x4 acc[2][4] = {};

  {
#pragma unroll
    for (int q = 0; q < 2; ++q) {
      int brow = w * 32 + q * 16 + (l >> 2);
      const unsigned short* gp = w1b + (size_t)brow * HH + (l & 3) * 8;
      GLDS16(gp, &Bs[0][w * 32 + q * 16][0]);
    }
    float4 xa = *reinterpret_cast<const float4*>(&x[xbase + aseg * 8]);
    float4 xb = *reinterpret_cast<const float4*>(&x[xbase + aseg * 8 + 4]);
    short8v v;
    v[0] = (short)f2bf(xa.x); v[1] = (short)f2bf(xa.y);
    v[2] = (short)f2bf(xa.z); v[3] = (short)f2bf(xa.w);
    v[4] = (short)f2bf(xb.x); v[5] = (short)f2bf(xb.y);
    v[6] = (short)f2bf(xb.z); v[7] = (short)f2bf(xb.w);
    *reinterpret_cast<short8v*>(&As[0][arow][aseg * 8]) = v;
  }

  for (int kt = 0; kt < HH / 32; ++kt) {
    const int cur = kt & 1, nxt = cur ^ 1;
    __syncthreads();

    float4 xa, xb;
    if (kt < HH / 32 - 1) {
      const int k0n = (kt + 1) * 32;
#pragma unroll
      for (int q = 0; q < 2; ++q) {
        int brow = w * 32 + q * 16 + (l >> 2);
        const unsigned short* gp = w1b + (size_t)brow * HH + k0n + (l & 3) * 8;
        GLDS16(gp, &Bs[nxt][w * 32 + q * 16][0]);
      }
      xa = *reinterpret_cast<const float4*>(&x[xbase + k0n + aseg * 8]);
      xb = *reinterpret_cast<const float4*>(&x[xbase + k0n + aseg * 8 + 4]);
    }

    short8v a[2], b[4];
#pragma unroll
    for (int mi = 0; mi < 2; ++mi)
      a[mi] = *reinterpret_cast<const short8v*>(&As[cur][wm * 32 + mi * 16 + (l & 15)][(l >> 4) * 8]);
#pragma unroll
    for (int ni = 0; ni < 4; ++ni)
      b[ni] = *reinterpret_cast<const short8v*>(&Bs[cur][wn * 64 + ni * 16 + (l & 15)][(l >> 4) * 8]);
#pragma unroll
    for (int mi = 0; mi < 2; ++mi)
#pragma unroll
      for (int ni = 0; ni < 4; ++ni)
        acc[mi][ni] = __builtin_amdgcn_mfma_f32_16x16x32_bf16(a[mi], b[ni], acc[mi][ni], 0, 0, 0);

    if (kt < HH / 32 - 1) {
      short8v v;
      v[0] = (short)f2bf(xa.x); v[1] = (short)f2bf(xa.y);
      v[2] = (short)f2bf(xa.z); v[3] = (short)f2bf(xa.w);
      v[4] = (short)f2bf(xb.x); v[5] = (short)f2bf(xb.y);
      v[6] = (short)f2bf(xb.z); v[7] = (short)f2bf(xb.w);
      *reinterpret_cast<short8v*>(&As[nxt][arow][aseg * 8]) = v;
    }
  }

  float bv[4];
#pragma unroll
  for (int ni = 0; ni < 4; ++ni) bv[ni] = b1[wn * 64 + ni * 16 + (l & 15)];
#pragma unroll
  for (int mi = 0; mi < 2; ++mi)
#pragma unroll
    for (int ni = 0; ni < 4; ++ni)
#pragma unroll
      for (int r = 0; r < 4; ++r) acc[mi][ni][r] += bv[ni];

  float ss[2][4];
#pragma unroll
  for (int mi = 0; mi < 2; ++mi)
#pragma unroll
    for (int r = 0; r < 4; ++r) {
      float s = 0.f;
#pragma unroll
      for (int ni = 0; ni < 4; ++ni) { float v = acc[mi][ni][r]; s += v * v; }
#pragma unroll
      for (int m = 1; m < 16; m <<= 1) s += __shfl_xor(s, m, 64);
      ss[mi][r] = s;
    }
  if ((l & 15) == 0) {
#pragma unroll
    for (int mi = 0; mi < 2; ++mi)
#pragma unroll
      for (int r = 0; r < 4; ++r)
        norms[wm * 32 + mi * 16 + (l >> 4) * 4 + r][wn] = ss[mi][r];
  }
  __syncthreads();

#pragma unroll
  for (int mi = 0; mi < 2; ++mi)
#pragma unroll
    for (int r = 0; r < 4; ++r) {
      int row = wm * 32 + mi * 16 + (l >> 4) * 4 + r;
      float tot = norms[row][0] + norms[row][1];
      float inv = 1.0f / fmaxf(sqrtf(tot), 1e-8f);
      size_t gbase = (size_t)(row0 + row) * D1;
#pragma unroll
      for (int ni = 0; ni < 4; ++ni) {
        int col = wn * 64 + ni * 16 + (l & 15);
        float v = acc[mi][ni][r];
        h[gbase + col] = v;
        xn[gbase + col] = v * inv;
      }
    }
}

// ---------------- K3a: per-chunk partials of S1 = xn^T @ h  ([128][128] per b) ----------------
__global__ __launch_bounds__(256) void k_s1_partial(const float* __restrict__ xn,
                                                    const float* __restrict__ h,
                                                    float* __restrict__ P1) {
  __shared__ float xs[8][128];
  __shared__ float hs[8][128];
  const int t = threadIdx.x;
  const int ch = blockIdx.x, b = blockIdx.y;
  const int ty = t >> 4, tx = t & 15;
  float acc[8][8] = {};
  const size_t base = ((size_t)b * NN + ch * ROWS_PER_CH) * D1;
  for (int s8 = 0; s8 < ROWS_PER_CH / 8; ++s8) {
    int r = t >> 5, c4 = (t & 31) * 4;
    *reinterpret_cast<float4*>(&xs[r][c4]) =
        *reinterpret_cast<const float4*>(&xn[base + (size_t)(s8 * 8 + r) * D1 + c4]);
    *reinterpret_cast<float4*>(&hs[r][c4]) =
        *reinterpret_cast<const float4*>(&h[base + (size_t)(s8 * 8 + r) * D1 + c4]);
    __syncthreads();
#pragma unroll
    for (int nn = 0; nn < 8; ++nn) {
      float a[8], bb[8];
#pragma unroll
      for (int i = 0; i < 8; ++i) a[i] = xs[nn][ty * 8 + i];
#pragma unroll
      for (int j = 0; j < 8; ++j) bb[j] = hs[nn][tx * 8 + j];
#pragma unroll
      for (int i = 0; i < 8; ++i)
#pragma unroll
        for (int j = 0; j < 8; ++j) acc[i][j] += a[i] * bb[j];
    }
    __syncthreads();
  }
  float* P = P1 + ((size_t)b * NCH + ch) * (D1 * D1);
#pragma unroll
  for (int i = 0; i < 8; ++i)
#pragma unroll
    for (int j4 = 0; j4 < 2; ++j4) {
      float4 v = make_float4(acc[i][j4 * 4 + 0], acc[i][j4 * 4 + 1],
                             acc[i][j4 * 4 + 2], acc[i][j4 * 4 + 3]);
      *reinterpret_cast<float4*>(&P[(size_t)(ty * 8 + i) * D1 + tx * 8 + j4 * 4]) = v;
    }
}

// ---------------- K4: fused reduce(P1)->S1(LDS) + M1 = S1@c1_lw^T/2047 ; R1 ----------------
// grid (4 d-chunks, 8 b), 256 threads
__global__ __launch_bounds__(256) void k_m1_fused(const float* __restrict__ P1,
                                                  const float* __restrict__ c1_lw,
                                                  const float* __restrict__ c1_rw,
                                                  float* __restrict__ M1, float* __restrict__ R1) {
  __shared__ float s_s[32][128];    // reduced S1 rows for this chunk (16 KB)
  __shared__ float lw_s[64][132];   // c1_lw padded (33.8 KB)
  const int t = threadIdx.x;
  const int dchunk = blockIdx.x;    // rows dchunk*32 .. +31
  const int b = blockIdx.y;
  const float inv = 1.0f / 2047.0f;

  // stage c1_lw [64][128] -> lw_s
#pragma unroll
  for (int q = 0; q < 8; ++q) {
    int idx4 = q * 256 + t;          // 0..2047 float4 units
    int o = idx4 >> 5, e4 = idx4 & 31;
    float4 v = *reinterpret_cast<const float4*>(&c1_lw[o * 128 + e4 * 4]);
    *reinterpret_cast<float4*>(&lw_s[o][e4 * 4]) = v;
  }
  // reduce P1 chunks into s_s
  const float* Pb = P1 + (size_t)b * NCH * (D1 * D1) + (size_t)(dchunk * 32) * D1;
#pragma unroll
  for (int q = 0; q < 4; ++q) {
    int idx4 = q * 256 + t;          // 0..1023 float4 over [32][32]
    int r = idx4 >> 5, e4 = idx4 & 31;
    float4 s = make_float4(0.f, 0.f, 0.f, 0.f);
#pragma unroll
    for (int c = 0; c < NCH; ++c) {
      float4 v = *reinterpret_cast<const float4*>(&Pb[(size_t)c * (D1 * D1) + r * D1 + e4 * 4]);
      s.x += v.x; s.y += v.y; s.z += v.z; s.w += v.w;
    }
    *reinterpret_cast<float4*>(&s_s[r][e4 * 4]) = s;
  }
  __syncthreads();

  // dot phase: thread tile 4 d-rows x 2 o-cols (o, o+32)
  const int dy = t >> 5;            // 0..7 -> rows dy*4..+3
  const int ox = t & 31;            // o and o+32
  float acc[4][2] = {};
  for (int e4 = 0; e4 < 32; ++e4) {
    float4 lw0 = *reinterpret_cast<const float4*>(&lw_s[ox][e4 * 4]);
    float4 lw1 = *reinterpret_cast<const float4*>(&lw_s[ox + 32][e4 * 4]);
#pragma unroll
    for (int i = 0; i < 4; ++i) {
      float4 sv = *reinterpret_cast<const float4*>(&s_s[dy * 4 + i][e4 * 4]);
      acc[i][0] += sv.x * lw0.x + sv.y * lw0.y + sv.z * lw0.z + sv.w * lw0.w;
      acc[i][1] += sv.x * lw1.x + sv.y * lw1.y + sv.z * lw1.z + sv.w * lw1.w;
    }
  }
#pragma unroll
  for (int i = 0; i < 4; ++i) {
    int d = dchunk * 32 + dy * 4 + i;
    M1[((size_t)b * D1 + d) * D2 + ox]      = acc[i][0] * inv;
    M1[((size_t)b * D1 + d) * D2 + ox + 32] = acc[i][1] * inv;
    if (b == 0) {
      R1[d * D2 + ox]      = c1_rw[ox * D1 + d]        - lw_s[ox][d] * inv;
      R1[d * D2 + ox + 32] = c1_rw[(ox + 32) * D1 + d] - lw_s[ox + 32][d] * inv;
    }
  }
}

// ---------------- K5: h1 = relu(xn@M1 + h@R1 + c1_lb) ----------------
__global__ __launch_bounds__(256) void k_h1(const float* __restrict__ xn, const float* __restrict__ h,
                                            const float* __restrict__ M1, const float* __restrict__ R1,
                                            const float* __restrict__ c1_lb, float* __restrict__ h1) {
  __shared__ float xs[64][17], hsh[64][17], Ms[16][D2], Rs[16][D2];
  const int t = threadIdx.x;
  const int row0 = blockIdx.x * 64;
  const int b = row0 >> 11;
  const int ty = t >> 4, tx = t & 15;
  float acc[4][4] = {};
  for (int k0 = 0; k0 < D1; k0 += 16) {
    {
      int r = t >> 2, ks = (t & 3) * 4;
      float4 v = *reinterpret_cast<const float4*>(&xn[(size_t)(row0 + r) * D1 + k0 + ks]);
      xs[r][ks] = v.x; xs[r][ks + 1] = v.y; xs[r][ks + 2] = v.z; xs[r][ks + 3] = v.w;
      float4 u = *reinterpret_cast<const float4*>(&h[(size_t)(row0 + r) * D1 + k0 + ks]);
      hsh[r][ks] = u.x; hsh[r][ks + 1] = u.y; hsh[r][ks + 2] = u.z; hsh[r][ks + 3] = u.w;
      int kk = t >> 4, o4 = (t & 15) * 4;
      *reinterpret_cast<float4*>(&Ms[kk][o4]) =
          *reinterpret_cast<const float4*>(&M1[(size_t)b * D1 * D2 + (size_t)(k0 + kk) * D2 + o4]);
      *reinterpret_cast<float4*>(&Rs[kk][o4]) =
          *reinterpret_cast<const float4*>(&R1[(size_t)(k0 + kk) * D2 + o4]);
    }
    __syncthreads();
#pragma unroll
    for (int kk = 0; kk < 16; ++kk) {
      float a[4], c[4], bm[4], br[4];
#pragma unroll
      for (int i = 0; i < 4; ++i) { a[i] = xs[ty * 4 + i][kk]; c[i] = hsh[ty * 4 + i][kk]; }
#pragma unroll
      for (int j = 0; j < 4; ++j) { bm[j] = Ms[kk][tx * 4 + j]; br[j] = Rs[kk][tx * 4 + j]; }
#pragma unroll
      for (int i = 0; i < 4; ++i)
#pragma unroll
        for (int j = 0; j < 4; ++j) acc[i][j] += a[i] * bm[j] + c[i] * br[j];
    }
    __syncthreads();
  }
#pragma unroll
  for (int i = 0; i < 4; ++i) {
    int r = row0 + ty * 4 + i;
#pragma unroll
    for (int j = 0; j < 4; ++j) {
      float v = acc[i][j] + c1_lb[tx * 4 + j];
      h1[(size_t)r * D2 + tx * 4 + j] = fmaxf(v, 0.0f);
    }
  }
}

// ---------------- K6a: per-chunk partials of S2 = xn^T @ h1 ([128][64] per b) ----------------
__global__ __launch_bounds__(256) void k_s2_partial(const float* __restrict__ xn,
                                                    const float* __restrict__ h1,
                                                    float* __restrict__ P2) {
  __shared__ float xs[8][128];
  __shared__ float hs[8][64];
  const int t = threadIdx.x;
  const int ch = blockIdx.x, b = blockIdx.y;
  const int ty = t >> 3, tx = t & 7;
  float acc[4][8] = {};
  const size_t xbase = ((size_t)b * NN + ch * ROWS_PER_CH) * D1;
  const size_t hbase = ((size_t)b * NN + ch * ROWS_PER_CH) * D2;
  for (int s8 = 0; s8 < ROWS_PER_CH / 8; ++s8) {
    int r = t >> 5, c4 = (t & 31) * 4;
    *reinterpret_cast<float4*>(&xs[r][c4]) =
        *reinterpret_cast<const float4*>(&xn[xbase + (size_t)(s8 * 8 + r) * D1 + c4]);
    if (t < 128) {
      int r2 = t >> 4, c42 = (t & 15) * 4;
      *reinterpret_cast<float4*>(&hs[r2][c42]) =
          *reinterpret_cast<const float4*>(&h1[hbase + (size_t)(s8 * 8 + r2) * D2 + c42]);
    }
    __syncthreads();
#pragma unroll
    for (int nn = 0; nn < 8; ++nn) {
      float a[4], bb[8];
#pragma unroll
      for (int i = 0; i < 4; ++i) a[i] = xs[nn][ty * 4 + i];
#pragma unroll
      for (int j = 0; j < 8; ++j) bb[j] = hs[nn][tx * 8 + j];
#pragma unroll
      for (int i = 0; i < 4; ++i)
#pragma unroll
        for (int j = 0; j < 8; ++j) acc[i][j] += a[i] * bb[j];
    }
    __syncthreads();
  }
  float* P = P2 + ((size_t)b * NCH + ch) * (D1 * D2);
#pragma unroll
  for (int i = 0; i < 4; ++i)
#pragma unroll
    for (int j4 = 0; j4 < 2; ++j4) {
      float4 v = make_float4(acc[i][j4 * 4 + 0], acc[i][j4 * 4 + 1],
                             acc[i][j4 * 4 + 2], acc[i][j4 * 4 + 3]);
      *reinterpret_cast<float4*>(&P[(size_t)(ty * 4 + i) * D2 + tx * 8 + j4 * 4]) = v;
    }
}

// ---------------- K7: fused reduce(P2) + m2 = S2@c2_lw/2047 ; r2 ----------------
// grid (4 d-chunks, 8 b), 256 threads (4 waves x 8 rows each)
__global__ __launch_bounds__(256) void k_m2_fused(const float* __restrict__ P2,
                                                  const float* __restrict__ c2_lw,
                                                  const float* __restrict__ c2_rw,
                                                  float* __restrict__ m2, float* __restrict__ r2) {
  const int t = threadIdx.x;
  const int dchunk = blockIdx.x, b = blockIdx.y;
  const int dy = t >> 6;           // wave 0..3
  const int o = t & 63;
  const float inv = 1.0f / 2047.0f;
  const float lw = c2_lw[o];
  const float* Pb = P2 + (size_t)b * NCH * (D1 * D2);
#pragma unroll
  for (int rr = 0; rr < 8; ++rr) {
    int d = dchunk * 32 + dy * 8 + rr;
    const float* p = Pb + (size_t)d * D2 + o;
    float s = 0.f;
#pragma unroll
    for (int c = 0; c < NCH; ++c) s += p[(size_t)c * (D1 * D2)];
    s *= lw;
#pragma unroll
    for (int m = 1; m < 64; m <<= 1) s += __shfl_xor(s, m, 64);
    if (o == 0) m2[b * D1 + d] = s * inv;
  }
  if (b == 0 && dchunk == 0 && t < D2) r2[t] = c2_rw[t] - c2_lw[t] * inv;
}

// ---------------- K8: out = sigmoid(xn.m2 + h1.r2 + c2_lb) * mask ----------------
__global__ __launch_bounds__(256) void k_out(const float* __restrict__ xn, const float* __restrict__ h1,
                                             const float* __restrict__ m2, const float* __restrict__ r2,
                                             const float* __restrict__ c2_lb, const float* __restrict__ mask,
                                             float* __restrict__ out) {
  int row = blockIdx.x * 4 + (threadIdx.x >> 6);
  int lane = threadIdx.x & 63;
  int b = row >> 11;
  float s = xn[(size_t)row * D1 + lane] * m2[b * D1 + lane]
          + xn[(size_t)row * D1 + 64 + lane] * m2[b * D1 + 64 + lane]
          + h1[(size_t)row * D2 + lane] * r2[lane];
#pragma unroll
  for (int m = 1; m < 64; m <<= 1) s += __shfl_xor(s, m, 64);
  if (lane == 0) {
    float v = s + c2_lb[0];
    out[row] = (1.0f / (1.0f + expf(-v))) * mask[row];
  }
}

extern "C" void kernel_launch(void* const* d_in, const int* in_sizes, int n_in,
                              void* d_out, int out_size, void* d_ws, size_t ws_size,
                              hipStream_t stream) {
  const float* x      = (const float*)d_in[0];
  const float* mask   = (const float*)d_in[1];
  const float* w1     = (const float*)d_in[2];
  const float* b1     = (const float*)d_in[3];
  const float* c1_lw  = (const float*)d_in[4];
  const float* c1_lb  = (const float*)d_in[5];
  const float* c1_rw  = (const float*)d_in[6];
  const float* c2_lw  = (const float*)d_in[7];
  const float* c2_lb  = (const float*)d_in[8];
  const float* c2_rw  = (const float*)d_in[9];
  float* ws  = (float*)d_ws;
  float* h   = ws + OFF_H;
  float* xn  = ws + OFF_XN;
  float* h1  = ws + OFF_H1;
  float* P1  = ws + OFF_P1;
  float* M1  = ws + OFF_M1;
  float* R1  = ws + OFF_R1;
  float* P2  = ws + OFF_P2;
  float* m2  = ws + OFF_M2;
  float* r2  = ws + OFF_R2;
  unsigned short* w1b = (unsigned short*)(ws + OFF_P1);  // reuses P1 region (written later)
  float* out = (float*)d_out;

  k_cvt_w1<<<dim3((D1 * HH) / 1024), dim3(256), 0, stream>>>(w1, w1b);
  k_gemm_h<<<dim3(BN / 64), dim3(256), 0, stream>>>(x, w1b, b1, h, xn);
  k_s1_partial<<<dim3(NCH, BB), dim3(256), 0, stream>>>(xn, h, P1);
  k_m1_fused<<<dim3(4, BB), dim3(256), 0, stream>>>(P1, c1_lw, c1_rw, M1, R1);
  k_h1<<<dim3(BN / 64), dim3(256), 0, stream>>>(xn, h, M1, R1, c1_lb, h1);
  k_s2_partial<<<dim3(NCH, BB), dim3(256), 0, stream>>>(xn, h1, P2);
  k_m2_fused<<<dim3(4, BB), dim3(256), 0, stream>>>(P2, c2_lw, c2_rw, m2, r2);
  k_out<<<dim3(BN / 4), dim3(256), 0, stream>>>(xn, h1, m2, r2, c2_lb, mask, out);
}

// Round 4
// 68.547 us; speedup vs baseline: 2.6122x; 1.6355x over previous
//
#include <hip/hip_runtime.h>
#include <hip/hip_bf16.h>
#include <math.h>

#define BB 8
#define NN 2048
#define HH 768
#define D1 128
#define D2 64
#define BN (BB*NN)            // 16384 rows total
#define NCH 16                // split-n chunks for S1/S2 partial reductions
#define ROWS_PER_CH (NN/NCH)  // 128

// workspace offsets (floats)
#define OFF_HB    0u          // bf16 [BN][128]
#define OFF_XNB   1048576u    // bf16 [BN][128]
#define OFF_HBT   2097152u    // bf16 [8][128][2048]
#define OFF_XNBT  3145728u    // bf16 [8][128][2048]
#define OFF_H1B   4194304u    // bf16 [BN][64]
#define OFF_H1BT  4718592u    // bf16 [8][64][2048]
#define OFF_P1    5242880u    // f32 [8][16][128][128]  (w1b bf16 aliases here pre-s1)
#define OFF_P2    7340032u    // f32 [8][16][128][64]
#define OFF_M1T   8388608u    // bf16 [8][64][128]
#define OFF_R1T   8421376u    // bf16 [64][128]
#define OFF_M2    8425472u    // f32 [8][128]
#define OFF_R2    8426496u    // f32 [64]

typedef __attribute__((ext_vector_type(8))) short short8v;
typedef __attribute__((ext_vector_type(4))) float f32x4;
typedef unsigned short USH;

__device__ __forceinline__ USH f2bf(float f) {
  unsigned int u = __builtin_bit_cast(unsigned int, f);
  u = (u + 0x7fffu + ((u >> 16) & 1u)) >> 16;
  return (USH)u;
}
__device__ __forceinline__ float bf2f(USH u) {
  return __builtin_bit_cast(float, ((unsigned int)u) << 16);
}

#define GLDS16(gp, lp)                                                        \
  __builtin_amdgcn_global_load_lds((const __attribute__((address_space(1))) void*)(gp), \
                                   (__attribute__((address_space(3))) void*)(lp), 16, 0, 0)

// ---------------- K0: convert w1 (fp32 [128][768]) -> bf16 ----------------
__global__ __launch_bounds__(256) void k_cvt_w1(const float* __restrict__ w1,
                                                USH* __restrict__ w1b) {
  int i = (blockIdx.x * 256 + threadIdx.x) * 4;
  float4 v = *reinterpret_cast<const float4*>(&w1[i]);
  ushort4 o;
  o.x = f2bf(v.x); o.y = f2bf(v.y); o.z = f2bf(v.z); o.w = f2bf(v.w);
  *reinterpret_cast<ushort4*>(&w1b[i]) = o;
}

// ---------------- K1: h = x @ w1^T + b1 (bf16 MFMA), fused norm, emit 4 bf16 views ----
__global__ __launch_bounds__(256) void k_gemm_h(const float* __restrict__ x,
                                                const USH* __restrict__ w1b,
                                                const float* __restrict__ b1,
                                                USH* __restrict__ hb,
                                                USH* __restrict__ xnb,
                                                USH* __restrict__ hbT,
                                                USH* __restrict__ xnbT) {
  __shared__ __align__(16) USH As[2][64][32];   // 8 KB
  __shared__ __align__(16) USH Bs[2][128][32];  // 16 KB
  __shared__ float norms[64][2];
  __shared__ __align__(16) USH T[128][72];      // transpose buffer (18.4 KB)

  const int t = threadIdx.x;
  const int w = t >> 6;
  const int l = t & 63;
  const int wm = w & 1;
  const int wn = w >> 1;
  const int row0 = blockIdx.x * 64;
  const int b_ = row0 >> 11;
  const int nloc = row0 & (NN - 1);

  const int arow = t >> 2;
  const int aseg = t & 3;
  const size_t xbase = (size_t)(row0 + arow) * HH;

  f32x4 acc[2][4] = {};

  {
#pragma unroll
    for (int q = 0; q < 2; ++q) {
      int brow = w * 32 + q * 16 + (l >> 2);
      const USH* gp = w1b + (size_t)brow * HH + (l & 3) * 8;
      GLDS16(gp, &Bs[0][w * 32 + q * 16][0]);
    }
    float4 xa = *reinterpret_cast<const float4*>(&x[xbase + aseg * 8]);
    float4 xb = *reinterpret_cast<const float4*>(&x[xbase + aseg * 8 + 4]);
    short8v v;
    v[0] = (short)f2bf(xa.x); v[1] = (short)f2bf(xa.y);
    v[2] = (short)f2bf(xa.z); v[3] = (short)f2bf(xa.w);
    v[4] = (short)f2bf(xb.x); v[5] = (short)f2bf(xb.y);
    v[6] = (short)f2bf(xb.z); v[7] = (short)f2bf(xb.w);
    *reinterpret_cast<short8v*>(&As[0][arow][aseg * 8]) = v;
  }

  for (int kt = 0; kt < HH / 32; ++kt) {
    const int cur = kt & 1, nxt = cur ^ 1;
    __syncthreads();

    float4 xa, xb;
    if (kt < HH / 32 - 1) {
      const int k0n = (kt + 1) * 32;
#pragma unroll
      for (int q = 0; q < 2; ++q) {
        int brow = w * 32 + q * 16 + (l >> 2);
        const USH* gp = w1b + (size_t)brow * HH + k0n + (l & 3) * 8;
        GLDS16(gp, &Bs[nxt][w * 32 + q * 16][0]);
      }
      xa = *reinterpret_cast<const float4*>(&x[xbase + k0n + aseg * 8]);
      xb = *reinterpret_cast<const float4*>(&x[xbase + k0n + aseg * 8 + 4]);
    }

    short8v a[2], b[4];
#pragma unroll
    for (int mi = 0; mi < 2; ++mi)
      a[mi] = *reinterpret_cast<const short8v*>(&As[cur][wm * 32 + mi * 16 + (l & 15)][(l >> 4) * 8]);
#pragma unroll
    for (int ni = 0; ni < 4; ++ni)
      b[ni] = *reinterpret_cast<const short8v*>(&Bs[cur][wn * 64 + ni * 16 + (l & 15)][(l >> 4) * 8]);
#pragma unroll
    for (int mi = 0; mi < 2; ++mi)
#pragma unroll
      for (int ni = 0; ni < 4; ++ni)
        acc[mi][ni] = __builtin_amdgcn_mfma_f32_16x16x32_bf16(a[mi], b[ni], acc[mi][ni], 0, 0, 0);

    if (kt < HH / 32 - 1) {
      short8v v;
      v[0] = (short)f2bf(xa.x); v[1] = (short)f2bf(xa.y);
      v[2] = (short)f2bf(xa.z); v[3] = (short)f2bf(xa.w);
      v[4] = (short)f2bf(xb.x); v[5] = (short)f2bf(xb.y);
      v[6] = (short)f2bf(xb.z); v[7] = (short)f2bf(xb.w);
      *reinterpret_cast<short8v*>(&As[nxt][arow][aseg * 8]) = v;
    }
  }

  // bias
  float bv[4];
#pragma unroll
  for (int ni = 0; ni < 4; ++ni) bv[ni] = b1[wn * 64 + ni * 16 + (l & 15)];
#pragma unroll
  for (int mi = 0; mi < 2; ++mi)
#pragma unroll
    for (int ni = 0; ni < 4; ++ni)
#pragma unroll
      for (int r = 0; r < 4; ++r) acc[mi][ni][r] += bv[ni];

  // row norms
  float ss[2][4];
#pragma unroll
  for (int mi = 0; mi < 2; ++mi)
#pragma unroll
    for (int r = 0; r < 4; ++r) {
      float s = 0.f;
#pragma unroll
      for (int ni = 0; ni < 4; ++ni) { float v = acc[mi][ni][r]; s += v * v; }
#pragma unroll
      for (int m = 1; m < 16; m <<= 1) s += __shfl_xor(s, m, 64);
      ss[mi][r] = s;
    }
  if ((l & 15) == 0) {
#pragma unroll
    for (int mi = 0; mi < 2; ++mi)
#pragma unroll
      for (int r = 0; r < 4; ++r)
        norms[wm * 32 + mi * 16 + (l >> 4) * 4 + r][wn] = ss[mi][r];
  }
  __syncthreads();

  float invr[2][4];
#pragma unroll
  for (int mi = 0; mi < 2; ++mi)
#pragma unroll
    for (int r = 0; r < 4; ++r) {
      int row = wm * 32 + mi * 16 + (l >> 4) * 4 + r;
      float tot = norms[row][0] + norms[row][1];
      invr[mi][r] = 1.0f / fmaxf(sqrtf(tot), 1e-8f);
    }

  // pass 1: h -> hb + T (transpose) -> hbT
#pragma unroll
  for (int mi = 0; mi < 2; ++mi)
#pragma unroll
    for (int ni = 0; ni < 4; ++ni)
#pragma unroll
      for (int r = 0; r < 4; ++r) {
        int rowL = wm * 32 + mi * 16 + (l >> 4) * 4 + r;
        int col  = wn * 64 + ni * 16 + (l & 15);
        USH hv = f2bf(acc[mi][ni][r]);
        hb[(size_t)(row0 + rowL) * D1 + col] = hv;
        T[col][rowL] = hv;
      }
  __syncthreads();
  {
    int d = t >> 1, seg = t & 1;
    size_t g = ((size_t)b_ * D1 + d) * NN + nloc + seg * 32;
#pragma unroll
    for (int k = 0; k < 4; ++k)
      *reinterpret_cast<short8v*>(&hbT[g + k * 8]) =
          *reinterpret_cast<const short8v*>(&T[d][seg * 32 + k * 8]);
  }
  __syncthreads();

  // pass 2: xn -> xnb + T -> xnbT
#pragma unroll
  for (int mi = 0; mi < 2; ++mi)
#pragma unroll
    for (int ni = 0; ni < 4; ++ni)
#pragma unroll
      for (int r = 0; r < 4; ++r) {
        int rowL = wm * 32 + mi * 16 + (l >> 4) * 4 + r;
        int col  = wn * 64 + ni * 16 + (l & 15);
        USH xv = f2bf(acc[mi][ni][r] * invr[mi][r]);
        xnb[(size_t)(row0 + rowL) * D1 + col] = xv;
        T[col][rowL] = xv;
      }
  __syncthreads();
  {
    int d = t >> 1, seg = t & 1;
    size_t g = ((size_t)b_ * D1 + d) * NN + nloc + seg * 32;
#pragma unroll
    for (int k = 0; k < 4; ++k)
      *reinterpret_cast<short8v*>(&xnbT[g + k * 8]) =
          *reinterpret_cast<const short8v*>(&T[d][seg * 32 + k * 8]);
  }
}

// ---------------- K2: S1 partials = xnbT(chunk) @ hbT(chunk)^T via MFMA ----------------
// grid (16 ch, 8 b); out [128 d][128 e] fp32 per block; K = 128 n-rows
__global__ __launch_bounds__(256) void k_s1(const USH* __restrict__ xnbT,
                                            const USH* __restrict__ hbT,
                                            float* __restrict__ P1) {
  __shared__ __align__(16) short TA[128][136];  // 34.8 KB (pad: 272B rows)
  __shared__ __align__(16) short TB[128][136];
  const int t = threadIdx.x;
  const int ch = blockIdx.x, b = blockIdx.y;
  const int n0 = ch * ROWS_PER_CH;
  {
    const int r0 = t >> 4;
    const int c8 = (t & 15) * 8;
#pragma unroll
    for (int p = 0; p < 8; ++p) {
      int row = p * 16 + r0;
      size_t g = ((size_t)b * D1 + row) * NN + n0 + c8;
      *reinterpret_cast<short8v*>(&TA[row][c8]) = *reinterpret_cast<const short8v*>(&xnbT[g]);
      *reinterpret_cast<short8v*>(&TB[row][c8]) = *reinterpret_cast<const short8v*>(&hbT[g]);
    }
  }
  __syncthreads();
  const int w = t >> 6, l = t & 63;
  const int wm = w & 1, wn = w >> 1;
  f32x4 acc[4][4] = {};
#pragma unroll
  for (int ks = 0; ks < 4; ++ks) {
    short8v a[4], bb[4];
#pragma unroll
    for (int fi = 0; fi < 4; ++fi)
      a[fi] = *reinterpret_cast<const short8v*>(&TA[wm * 64 + fi * 16 + (l & 15)][ks * 32 + (l >> 4) * 8]);
#pragma unroll
    for (int fj = 0; fj < 4; ++fj)
      bb[fj] = *reinterpret_cast<const short8v*>(&TB[wn * 64 + fj * 16 + (l & 15)][ks * 32 + (l >> 4) * 8]);
#pragma unroll
    for (int fi = 0; fi < 4; ++fi)
#pragma unroll
      for (int fj = 0; fj < 4; ++fj)
        acc[fi][fj] = __builtin_amdgcn_mfma_f32_16x16x32_bf16(a[fi], bb[fj], acc[fi][fj], 0, 0, 0);
  }
  float* P = P1 + ((size_t)b * NCH + ch) * (D1 * D1);
#pragma unroll
  for (int fi = 0; fi < 4; ++fi)
#pragma unroll
    for (int fj = 0; fj < 4; ++fj)
#pragma unroll
      for (int r = 0; r < 4; ++r) {
        int row = wm * 64 + fi * 16 + (l >> 4) * 4 + r;
        int col = wn * 64 + fj * 16 + (l & 15);
        P[(size_t)row * D1 + col] = acc[fi][fj][r];
      }
}

// ---------------- K3: fused reduce(P1) + M1T = (S1@c1_lw^T/2047)^T ; R1T (bf16) --------
__global__ __launch_bounds__(256) void k_m1_fused(const float* __restrict__ P1,
                                                  const float* __restrict__ c1_lw,
                                                  const float* __restrict__ c1_rw,
                                                  USH* __restrict__ M1T, USH* __restrict__ R1T) {
  __shared__ float s_s[32][128];
  __shared__ float lw_s[64][132];
  const int t = threadIdx.x;
  const int dchunk = blockIdx.x;
  const int b = blockIdx.y;
  const float inv = 1.0f / 2047.0f;

#pragma unroll
  for (int q = 0; q < 8; ++q) {
    int idx4 = q * 256 + t;
    int o = idx4 >> 5, e4 = idx4 & 31;
    float4 v = *reinterpret_cast<const float4*>(&c1_lw[o * 128 + e4 * 4]);
    *reinterpret_cast<float4*>(&lw_s[o][e4 * 4]) = v;
  }
  const float* Pb = P1 + (size_t)b * NCH * (D1 * D1) + (size_t)(dchunk * 32) * D1;
#pragma unroll
  for (int q = 0; q < 4; ++q) {
    int idx4 = q * 256 + t;
    int r = idx4 >> 5, e4 = idx4 & 31;
    float4 s = make_float4(0.f, 0.f, 0.f, 0.f);
#pragma unroll
    for (int c = 0; c < NCH; ++c) {
      float4 v = *reinterpret_cast<const float4*>(&Pb[(size_t)c * (D1 * D1) + r * D1 + e4 * 4]);
      s.x += v.x; s.y += v.y; s.z += v.z; s.w += v.w;
    }
    *reinterpret_cast<float4*>(&s_s[r][e4 * 4]) = s;
  }
  __syncthreads();

  const int dy = t >> 5;
  const int ox = t & 31;
  float acc[4][2] = {};
  for (int e4 = 0; e4 < 32; ++e4) {
    float4 lw0 = *reinterpret_cast<const float4*>(&lw_s[ox][e4 * 4]);
    float4 lw1 = *reinterpret_cast<const float4*>(&lw_s[ox + 32][e4 * 4]);
#pragma unroll
    for (int i = 0; i < 4; ++i) {
      float4 sv = *reinterpret_cast<const float4*>(&s_s[dy * 4 + i][e4 * 4]);
      acc[i][0] += sv.x * lw0.x + sv.y * lw0.y + sv.z * lw0.z + sv.w * lw0.w;
      acc[i][1] += sv.x * lw1.x + sv.y * lw1.y + sv.z * lw1.z + sv.w * lw1.w;
    }
  }
#pragma unroll
  for (int i = 0; i < 4; ++i) {
    int d = dchunk * 32 + dy * 4 + i;
    M1T[((size_t)b * D2 + ox) * D1 + d]        = f2bf(acc[i][0] * inv);
    M1T[((size_t)b * D2 + ox + 32) * D1 + d]   = f2bf(acc[i][1] * inv);
    if (b == 0) {
      R1T[ox * D1 + d]        = f2bf(c1_rw[ox * D1 + d]        - lw_s[ox][d] * inv);
      R1T[(ox + 32) * D1 + d] = f2bf(c1_rw[(ox + 32) * D1 + d] - lw_s[ox + 32][d] * inv);
    }
  }
}

// ---------------- K4: h1 = relu([xnb|hb] @ [M1T|R1T]^T + c1_lb) via MFMA (K=256) --------
// grid BN/64; emits h1b [n][64] + h1bT [b][64][2048]
__global__ __launch_bounds__(256) void k_h1(const USH* __restrict__ xnb,
                                            const USH* __restrict__ hb,
                                            const USH* __restrict__ M1T,
                                            const USH* __restrict__ R1T,
                                            const float* __restrict__ c1_lb,
                                            USH* __restrict__ h1b,
                                            USH* __restrict__ h1bT) {
  __shared__ __align__(16) short TA[64][280];   // 35 KB (560B rows)
  __shared__ __align__(16) short TB[64][280];   // 35 KB
  __shared__ __align__(16) USH  T2[64][72];     // 9.2 KB
  const int t = threadIdx.x;
  const int row0 = blockIdx.x * 64;
  const int b = row0 >> 11, nloc = row0 & (NN - 1);
  {
    const int row = t >> 2, seg = t & 3;
#pragma unroll
    for (int j = 0; j < 4; ++j) {
      int e = seg * 32 + j * 8;
      *reinterpret_cast<short8v*>(&TA[row][e]) =
          *reinterpret_cast<const short8v*>(&xnb[(size_t)(row0 + row) * D1 + e]);
      *reinterpret_cast<short8v*>(&TA[row][128 + e]) =
          *reinterpret_cast<const short8v*>(&hb[(size_t)(row0 + row) * D1 + e]);
      *reinterpret_cast<short8v*>(&TB[row][e]) =
          *reinterpret_cast<const short8v*>(&M1T[((size_t)b * D2 + row) * D1 + e]);
      *reinterpret_cast<short8v*>(&TB[row][128 + e]) =
          *reinterpret_cast<const short8v*>(&R1T[(size_t)row * D1 + e]);
    }
  }
  __syncthreads();
  const int w = t >> 6, l = t & 63;
  const int wm = w & 1, wn = w >> 1;
  f32x4 acc[2][2] = {};
#pragma unroll
  for (int ks = 0; ks < 8; ++ks) {
    short8v a[2], bb[2];
#pragma unroll
    for (int i = 0; i < 2; ++i)
      a[i] = *reinterpret_cast<const short8v*>(&TA[wm * 32 + i * 16 + (l & 15)][ks * 32 + (l >> 4) * 8]);
#pragma unroll
    for (int j = 0; j < 2; ++j)
      bb[j] = *reinterpret_cast<const short8v*>(&TB[wn * 32 + j * 16 + (l & 15)][ks * 32 + (l >> 4) * 8]);
#pragma unroll
    for (int i = 0; i < 2; ++i)
#pragma unroll
      for (int j = 0; j < 2; ++j)
        acc[i][j] = __builtin_amdgcn_mfma_f32_16x16x32_bf16(a[i], bb[j], acc[i][j], 0, 0, 0);
  }
#pragma unroll
  for (int i = 0; i < 2; ++i)
#pragma unroll
    for (int j = 0; j < 2; ++j) {
      int col = wn * 32 + j * 16 + (l & 15);
      float lb = c1_lb[col];
#pragma unroll
      for (int r = 0; r < 4; ++r) {
        int rowL = wm * 32 + i * 16 + (l >> 4) * 4 + r;
        USH hv = f2bf(fmaxf(acc[i][j][r] + lb, 0.0f));
        h1b[(size_t)(row0 + rowL) * D2 + col] = hv;
        T2[col][rowL] = hv;
      }
    }
  __syncthreads();
  {
    int col = t >> 2, seg = t & 3;
    size_t g = ((size_t)b * D2 + col) * NN + nloc + seg * 16;
    *reinterpret_cast<short8v*>(&h1bT[g]) =
        *reinterpret_cast<const short8v*>(&T2[col][seg * 16]);
    *reinterpret_cast<short8v*>(&h1bT[g + 8]) =
        *reinterpret_cast<const short8v*>(&T2[col][seg * 16 + 8]);
  }
}

// ---------------- K5: S2 partials = xnbT(chunk) @ h1bT(chunk)^T via MFMA ----------------
__global__ __launch_bounds__(256) void k_s2(const USH* __restrict__ xnbT,
                                            const USH* __restrict__ h1bT,
                                            float* __restrict__ P2) {
  __shared__ __align__(16) short TA[128][136];
  __shared__ __align__(16) short TB[64][136];
  const int t = threadIdx.x;
  const int ch = blockIdx.x, b = blockIdx.y;
  const int n0 = ch * ROWS_PER_CH;
  {
    const int r0 = t >> 4;
    const int c8 = (t & 15) * 8;
#pragma unroll
    for (int p = 0; p < 8; ++p) {
      int row = p * 16 + r0;
      *reinterpret_cast<short8v*>(&TA[row][c8]) =
          *reinterpret_cast<const short8v*>(&xnbT[((size_t)b * D1 + row) * NN + n0 + c8]);
    }
#pragma unroll
    for (int p = 0; p < 4; ++p) {
      int row = p * 16 + r0;
      *reinterpret_cast<short8v*>(&TB[row][c8]) =
          *reinterpret_cast<const short8v*>(&h1bT[((size_t)b * D2 + row) * NN + n0 + c8]);
    }
  }
  __syncthreads();
  const int w = t >> 6, l = t & 63;
  const int wm = w & 1, wn = w >> 1;   // wm: d-half(64), wn: o-half(32)
  f32x4 acc[4][2] = {};
#pragma unroll
  for (int ks = 0; ks < 4; ++ks) {
    short8v a[4], bb[2];
#pragma unroll
    for (int fi = 0; fi < 4; ++fi)
      a[fi] = *reinterpret_cast<const short8v*>(&TA[wm * 64 + fi * 16 + (l & 15)][ks * 32 + (l >> 4) * 8]);
#pragma unroll
    for (int fj = 0; fj < 2; ++fj)
      bb[fj] = *reinterpret_cast<const short8v*>(&TB[wn * 32 + fj * 16 + (l & 15)][ks * 32 + (l >> 4) * 8]);
#pragma unroll
    for (int fi = 0; fi < 4; ++fi)
#pragma unroll
      for (int fj = 0; fj < 2; ++fj)
        acc[fi][fj] = __builtin_amdgcn_mfma_f32_16x16x32_bf16(a[fi], bb[fj], acc[fi][fj], 0, 0, 0);
  }
  float* P = P2 + ((size_t)b * NCH + ch) * (D1 * D2);
#pragma unroll
  for (int fi = 0; fi < 4; ++fi)
#pragma unroll
    for (int fj = 0; fj < 2; ++fj)
#pragma unroll
      for (int r = 0; r < 4; ++r) {
        int row = wm * 64 + fi * 16 + (l >> 4) * 4 + r;
        int col = wn * 32 + fj * 16 + (l & 15);
        P[(size_t)row * D2 + col] = acc[fi][fj][r];
      }
}

// ---------------- K6: fused reduce(P2) + m2 = S2@c2_lw/2047 ; r2 (fp32) ----------------
__global__ __launch_bounds__(256) void k_m2_fused(const float* __restrict__ P2,
                                                  const float* __restrict__ c2_lw,
                                                  const float* __restrict__ c2_rw,
                                                  float* __restrict__ m2, float* __restrict__ r2) {
  const int t = threadIdx.x;
  const int dchunk = blockIdx.x, b = blockIdx.y;
  const int dy = t >> 6;
  const int o = t & 63;
  const float inv = 1.0f / 2047.0f;
  const float lw = c2_lw[o];
  const float* Pb = P2 + (size_t)b * NCH * (D1 * D2);
#pragma unroll
  for (int rr = 0; rr < 8; ++rr) {
    int d = dchunk * 32 + dy * 8 + rr;
    const float* p = Pb + (size_t)d * D2 + o;
    float s = 0.f;
#pragma unroll
    for (int c = 0; c < NCH; ++c) s += p[(size_t)c * (D1 * D2)];
    s *= lw;
#pragma unroll
    for (int m = 1; m < 64; m <<= 1) s += __shfl_xor(s, m, 64);
    if (o == 0) m2[b * D1 + d] = s * inv;
  }
  if (b == 0 && dchunk == 0 && t < D2) r2[t] = c2_rw[t] - c2_lw[t] * inv;
}

// ---------------- K7: out = sigmoid(xnb.m2 + h1b.r2 + c2_lb) * mask ----------------
__global__ __launch_bounds__(256) void k_out(const USH* __restrict__ xnb,
                                             const USH* __restrict__ h1b,
                                             const float* __restrict__ m2,
                                             const float* __restrict__ r2,
                                             const float* __restrict__ c2_lb,
                                             const float* __restrict__ mask,
                                             float* __restrict__ out) {
  int row = blockIdx.x * 4 + (threadIdx.x >> 6);
  int lane = threadIdx.x & 63;
  int b = row >> 11;
  float s = bf2f(xnb[(size_t)row * D1 + lane]) * m2[b * D1 + lane]
          + bf2f(xnb[(size_t)row * D1 + 64 + lane]) * m2[b * D1 + 64 + lane]
          + bf2f(h1b[(size_t)row * D2 + lane]) * r2[lane];
#pragma unroll
  for (int m = 1; m < 64; m <<= 1) s += __shfl_xor(s, m, 64);
  if (lane == 0) {
    float v = s + c2_lb[0];
    out[row] = (1.0f / (1.0f + expf(-v))) * mask[row];
  }
}

extern "C" void kernel_launch(void* const* d_in, const int* in_sizes, int n_in,
                              void* d_out, int out_size, void* d_ws, size_t ws_size,
                              hipStream_t stream) {
  const float* x      = (const float*)d_in[0];
  const float* mask   = (const float*)d_in[1];
  const float* w1     = (const float*)d_in[2];
  const float* b1     = (const float*)d_in[3];
  const float* c1_lw  = (const float*)d_in[4];
  const float* c1_lb  = (const float*)d_in[5];
  const float* c1_rw  = (const float*)d_in[6];
  const float* c2_lw  = (const float*)d_in[7];
  const float* c2_lb  = (const float*)d_in[8];
  const float* c2_rw  = (const float*)d_in[9];
  float* ws  = (float*)d_ws;
  USH* hb    = (USH*)(ws + OFF_HB);
  USH* xnb   = (USH*)(ws + OFF_XNB);
  USH* hbT   = (USH*)(ws + OFF_HBT);
  USH* xnbT  = (USH*)(ws + OFF_XNBT);
  USH* h1b   = (USH*)(ws + OFF_H1B);
  USH* h1bT  = (USH*)(ws + OFF_H1BT);
  float* P1  = ws + OFF_P1;
  float* P2  = ws + OFF_P2;
  USH* M1T   = (USH*)(ws + OFF_M1T);
  USH* R1T   = (USH*)(ws + OFF_R1T);
  float* m2  = ws + OFF_M2;
  float* r2  = ws + OFF_R2;
  USH* w1b   = (USH*)(ws + OFF_P1);  // aliases P1 (P1 written only after gemm_h done)
  float* out = (float*)d_out;

  k_cvt_w1<<<dim3((D1 * HH) / 1024), dim3(256), 0, stream>>>(w1, w1b);
  k_gemm_h<<<dim3(BN / 64), dim3(256), 0, stream>>>(x, w1b, b1, hb, xnb, hbT, xnbT);
  k_s1<<<dim3(NCH, BB), dim3(256), 0, stream>>>(xnbT, hbT, P1);
  k_m1_fused<<<dim3(4, BB), dim3(256), 0, stream>>>(P1, c1_lw, c1_rw, M1T, R1T);
  k_h1<<<dim3(BN / 64), dim3(256), 0, stream>>>(xnb, hb, M1T, R1T, c1_lb, h1b, h1bT);
  k_s2<<<dim3(NCH, BB), dim3(256), 0, stream>>>(xnbT, h1bT, P2);
  k_m2_fused<<<dim3(4, BB), dim3(256), 0, stream>>>(P2, c2_lw, c2_rw, m2, r2);
  k_out<<<dim3(BN / 4), dim3(256), 0, stream>>>(xnb, h1b, m2, r2, c2_lb, mask, out);
}

// Round 5
// 60.622 us; speedup vs baseline: 2.9536x; 1.1307x over previous
//
#include <hip/hip_runtime.h>
#include <hip/hip_bf16.h>
#include <math.h>

#define BB 8
#define NN 2048
#define HH 768
#define D1 128
#define D2 64
#define BN (BB*NN)            // 16384 rows total
#define NCH 16                // split-n chunks for S1/S2 partial reductions
#define ROWS_PER_CH (NN/NCH)  // 128

// workspace offsets (floats)
#define OFF_XNB   0u          // bf16 [BN][128]
#define OFF_XNBT  1048576u    // bf16 [8][128][2048]
#define OFF_NRM   2097152u    // f32  [BN]
#define OFF_H1B   2113536u    // bf16 [BN][64]
#define OFF_H1BT  2637824u    // bf16 [8][64][2048]
#define OFF_P1    3162112u    // f32 [8][16][128][128]  (w1b bf16 aliases here pre-s1)
#define OFF_P2    5259264u    // f32 [8][16][128][64]
#define OFF_M1T   6307840u    // bf16 [8][64][128]
#define OFF_R1T   6340608u    // bf16 [64][128]
#define OFF_M2    6344704u    // f32 [8][128]
#define OFF_R2    6345728u    // f32 [64]

typedef __attribute__((ext_vector_type(8))) short short8v;
typedef __attribute__((ext_vector_type(4))) float f32x4;
typedef unsigned short USH;

__device__ __forceinline__ USH f2bf(float f) {
  unsigned int u = __builtin_bit_cast(unsigned int, f);
  u = (u + 0x7fffu + ((u >> 16) & 1u)) >> 16;
  return (USH)u;
}
__device__ __forceinline__ float bf2f(USH u) {
  return __builtin_bit_cast(float, ((unsigned int)u) << 16);
}

#define GLDS16(gp, lp)                                                        \
  __builtin_amdgcn_global_load_lds((const __attribute__((address_space(1))) void*)(gp), \
                                   (__attribute__((address_space(3))) void*)(lp), 16, 0, 0)

// ---------------- K0: convert w1 (fp32 [128][768]) -> bf16 ----------------
__global__ __launch_bounds__(256) void k_cvt_w1(const float* __restrict__ w1,
                                                USH* __restrict__ w1b) {
  int i = (blockIdx.x * 256 + threadIdx.x) * 4;
  float4 v = *reinterpret_cast<const float4*>(&w1[i]);
  ushort4 o;
  o.x = f2bf(v.x); o.y = f2bf(v.y); o.z = f2bf(v.z); o.w = f2bf(v.w);
  *reinterpret_cast<ushort4*>(&w1b[i]) = o;
}

// ---------------- K1: h = x @ w1^T + b1 (bf16 MFMA, BM=32 BK=64, swizzled LDS) --------
// emits xnb [n][128], xnbT [b][128][2048], nrm [n]   (h == xn * nrm, never stored)
__global__ __launch_bounds__(256) void k_gemm_h(const float* __restrict__ x,
                                                const USH* __restrict__ w1b,
                                                const float* __restrict__ b1,
                                                USH* __restrict__ xnb,
                                                USH* __restrict__ xnbT,
                                                float* __restrict__ nrm) {
  __shared__ __align__(16) USH As[2][32][64];   // 8 KB  (slot-swizzled)
  __shared__ __align__(16) USH Bs[2][128][64];  // 32 KB (slot-swizzled)
  __shared__ float norms[32][2];
  __shared__ __align__(16) USH T[128][40];      // 10 KB transpose buffer

  const int t = threadIdx.x;
  const int w = t >> 6, l = t & 63;
  const int wm = w & 1, wn = w >> 1;
  const int row0 = blockIdx.x * 32;
  const int b_ = row0 >> 11, nloc = row0 & (NN - 1);

  // A staging: thread -> row t>>3, logical k-slot t&7 (8 elems); physical slot swizzled
  const int arow = t >> 3, aseg = t & 7;
  const int aslot = aseg ^ (arow & 7);
  const size_t xbase = (size_t)(row0 + arow) * HH;
  // B staging: wave w covers rows w*32..+31 in 4 GLDS16 (8 rows each); source pre-swizzled
  const int brow_l = w * 32 + (l >> 3);

  f32x4 acc[4] = {};

  {  // prologue: buffer 0
#pragma unroll
    for (int q = 0; q < 4; ++q) {
      int brow = brow_l + q * 8;
      int gslot = (l & 7) ^ (brow & 7);
      GLDS16(w1b + (size_t)brow * HH + gslot * 8, &Bs[0][w * 32 + q * 8][0]);
    }
    float4 xa = *reinterpret_cast<const float4*>(&x[xbase + aseg * 8]);
    float4 xb = *reinterpret_cast<const float4*>(&x[xbase + aseg * 8 + 4]);
    short8v v;
    v[0] = (short)f2bf(xa.x); v[1] = (short)f2bf(xa.y);
    v[2] = (short)f2bf(xa.z); v[3] = (short)f2bf(xa.w);
    v[4] = (short)f2bf(xb.x); v[5] = (short)f2bf(xb.y);
    v[6] = (short)f2bf(xb.z); v[7] = (short)f2bf(xb.w);
    *reinterpret_cast<short8v*>(&As[0][arow][aslot * 8]) = v;
  }

  for (int kt = 0; kt < HH / 64; ++kt) {
    const int cur = kt & 1, nxt = cur ^ 1;
    __syncthreads();

    float4 xa, xb;
    if (kt < HH / 64 - 1) {
      const int k0n = (kt + 1) * 64;
#pragma unroll
      for (int q = 0; q < 4; ++q) {
        int brow = brow_l + q * 8;
        int gslot = (l & 7) ^ (brow & 7);
        GLDS16(w1b + (size_t)brow * HH + k0n + gslot * 8, &Bs[nxt][w * 32 + q * 8][0]);
      }
      xa = *reinterpret_cast<const float4*>(&x[xbase + k0n + aseg * 8]);
      xb = *reinterpret_cast<const float4*>(&x[xbase + k0n + aseg * 8 + 4]);
    }

    const int ar = wm * 16 + (l & 15);
#pragma unroll
    for (int ks = 0; ks < 2; ++ks) {
      short8v a = *reinterpret_cast<const short8v*>(
          &As[cur][ar][((ks * 4 + (l >> 4)) ^ (ar & 7)) * 8]);
#pragma unroll
      for (int ni = 0; ni < 4; ++ni) {
        int br = wn * 64 + ni * 16 + (l & 15);
        short8v b = *reinterpret_cast<const short8v*>(
            &Bs[cur][br][((ks * 4 + (l >> 4)) ^ (br & 7)) * 8]);
        acc[ni] = __builtin_amdgcn_mfma_f32_16x16x32_bf16(a, b, acc[ni], 0, 0, 0);
      }
    }

    if (kt < HH / 64 - 1) {
      short8v v;
      v[0] = (short)f2bf(xa.x); v[1] = (short)f2bf(xa.y);
      v[2] = (short)f2bf(xa.z); v[3] = (short)f2bf(xa.w);
      v[4] = (short)f2bf(xb.x); v[5] = (short)f2bf(xb.y);
      v[6] = (short)f2bf(xb.z); v[7] = (short)f2bf(xb.w);
      *reinterpret_cast<short8v*>(&As[nxt][arow][aslot * 8]) = v;
    }
  }

  // epilogue: bias, row-norm, write xnb + xnbT + nrm
  float bv[4];
#pragma unroll
  for (int ni = 0; ni < 4; ++ni) bv[ni] = b1[wn * 64 + ni * 16 + (l & 15)];
#pragma unroll
  for (int ni = 0; ni < 4; ++ni)
#pragma unroll
    for (int r = 0; r < 4; ++r) acc[ni][r] += bv[ni];

#pragma unroll
  for (int r = 0; r < 4; ++r) {
    float s = 0.f;
#pragma unroll
    for (int ni = 0; ni < 4; ++ni) { float v = acc[ni][r]; s += v * v; }
#pragma unroll
    for (int m = 1; m < 16; m <<= 1) s += __shfl_xor(s, m, 64);
    if ((l & 15) == 0) norms[wm * 16 + (l >> 4) * 4 + r][wn] = s;
  }
  __syncthreads();

#pragma unroll
  for (int r = 0; r < 4; ++r) {
    int row = wm * 16 + (l >> 4) * 4 + r;
    float tot = norms[row][0] + norms[row][1];
    float ncl = fmaxf(sqrtf(tot), 1e-8f);
    float inv = 1.0f / ncl;
    if (wn == 0 && (l & 15) == 0) nrm[row0 + row] = ncl;
    size_t gbase = (size_t)(row0 + row) * D1;
#pragma unroll
    for (int ni = 0; ni < 4; ++ni) {
      int col = wn * 64 + ni * 16 + (l & 15);
      USH xv = f2bf(acc[ni][r] * inv);
      xnb[gbase + col] = xv;
      T[col][row] = xv;
    }
  }
  __syncthreads();
  {
    int d = t >> 1, seg = t & 1;
    size_t g = ((size_t)b_ * D1 + d) * NN + nloc + seg * 16;
    *reinterpret_cast<short8v*>(&xnbT[g]) =
        *reinterpret_cast<const short8v*>(&T[d][seg * 16]);
    *reinterpret_cast<short8v*>(&xnbT[g + 8]) =
        *reinterpret_cast<const short8v*>(&T[d][seg * 16 + 8]);
  }
}

// ---------------- K2: S1 partials = xnT(chunk) @ (diag(nrm) xn)(chunk) via MFMA --------
__global__ __launch_bounds__(256) void k_s1(const USH* __restrict__ xnbT,
                                            const float* __restrict__ nrm,
                                            float* __restrict__ P1) {
  __shared__ __align__(16) short TA[128][136];
  __shared__ __align__(16) short TB[128][136];
  const int t = threadIdx.x;
  const int ch = blockIdx.x, b = blockIdx.y;
  const int n0 = ch * ROWS_PER_CH;
  {
    const int r0 = t >> 4;
    const int c8 = (t & 15) * 8;
    float4 nva = *reinterpret_cast<const float4*>(&nrm[(size_t)b * NN + n0 + c8]);
    float4 nvb = *reinterpret_cast<const float4*>(&nrm[(size_t)b * NN + n0 + c8 + 4]);
    float nv[8] = {nva.x, nva.y, nva.z, nva.w, nvb.x, nvb.y, nvb.z, nvb.w};
#pragma unroll
    for (int p = 0; p < 8; ++p) {
      int row = p * 16 + r0;
      short8v v = *reinterpret_cast<const short8v*>(&xnbT[((size_t)b * D1 + row) * NN + n0 + c8]);
      *reinterpret_cast<short8v*>(&TA[row][c8]) = v;
      short8v hv;
#pragma unroll
      for (int j = 0; j < 8; ++j) hv[j] = (short)f2bf(bf2f((USH)v[j]) * nv[j]);
      *reinterpret_cast<short8v*>(&TB[row][c8]) = hv;
    }
  }
  __syncthreads();
  const int w = t >> 6, l = t & 63;
  const int wm = w & 1, wn = w >> 1;
  f32x4 acc[4][4] = {};
#pragma unroll
  for (int ks = 0; ks < 4; ++ks) {
    short8v a[4], bb[4];
#pragma unroll
    for (int fi = 0; fi < 4; ++fi)
      a[fi] = *reinterpret_cast<const short8v*>(&TA[wm * 64 + fi * 16 + (l & 15)][ks * 32 + (l >> 4) * 8]);
#pragma unroll
    for (int fj = 0; fj < 4; ++fj)
      bb[fj] = *reinterpret_cast<const short8v*>(&TB[wn * 64 + fj * 16 + (l & 15)][ks * 32 + (l >> 4) * 8]);
#pragma unroll
    for (int fi = 0; fi < 4; ++fi)
#pragma unroll
      for (int fj = 0; fj < 4; ++fj)
        acc[fi][fj] = __builtin_amdgcn_mfma_f32_16x16x32_bf16(a[fi], bb[fj], acc[fi][fj], 0, 0, 0);
  }
  float* P = P1 + ((size_t)b * NCH + ch) * (D1 * D1);
#pragma unroll
  for (int fi = 0; fi < 4; ++fi)
#pragma unroll
    for (int fj = 0; fj < 4; ++fj)
#pragma unroll
      for (int r = 0; r < 4; ++r) {
        int row = wm * 64 + fi * 16 + (l >> 4) * 4 + r;
        int col = wn * 64 + fj * 16 + (l & 15);
        P[(size_t)row * D1 + col] = acc[fi][fj][r];
      }
}

// ---------------- K3: fused reduce(P1) + M1T = (S1@c1_lw^T/2047)^T ; R1T (bf16) --------
__global__ __launch_bounds__(256) void k_m1_fused(const float* __restrict__ P1,
                                                  const float* __restrict__ c1_lw,
                                                  const float* __restrict__ c1_rw,
                                                  USH* __restrict__ M1T, USH* __restrict__ R1T) {
  __shared__ float s_s[32][128];
  __shared__ float lw_s[64][132];
  const int t = threadIdx.x;
  const int dchunk = blockIdx.x;
  const int b = blockIdx.y;
  const float inv = 1.0f / 2047.0f;

#pragma unroll
  for (int q = 0; q < 8; ++q) {
    int idx4 = q * 256 + t;
    int o = idx4 >> 5, e4 = idx4 & 31;
    float4 v = *reinterpret_cast<const float4*>(&c1_lw[o * 128 + e4 * 4]);
    *reinterpret_cast<float4*>(&lw_s[o][e4 * 4]) = v;
  }
  const float* Pb = P1 + (size_t)b * NCH * (D1 * D1) + (size_t)(dchunk * 32) * D1;
#pragma unroll
  for (int q = 0; q < 4; ++q) {
    int idx4 = q * 256 + t;
    int r = idx4 >> 5, e4 = idx4 & 31;
    float4 s = make_float4(0.f, 0.f, 0.f, 0.f);
#pragma unroll
    for (int c = 0; c < NCH; ++c) {
      float4 v = *reinterpret_cast<const float4*>(&Pb[(size_t)c * (D1 * D1) + r * D1 + e4 * 4]);
      s.x += v.x; s.y += v.y; s.z += v.z; s.w += v.w;
    }
    *reinterpret_cast<float4*>(&s_s[r][e4 * 4]) = s;
  }
  __syncthreads();

  const int dy = t >> 5;
  const int ox = t & 31;
  float acc[4][2] = {};
  for (int e4 = 0; e4 < 32; ++e4) {
    float4 lw0 = *reinterpret_cast<const float4*>(&lw_s[ox][e4 * 4]);
    float4 lw1 = *reinterpret_cast<const float4*>(&lw_s[ox + 32][e4 * 4]);
#pragma unroll
    for (int i = 0; i < 4; ++i) {
      float4 sv = *reinterpret_cast<const float4*>(&s_s[dy * 4 + i][e4 * 4]);
      acc[i][0] += sv.x * lw0.x + sv.y * lw0.y + sv.z * lw0.z + sv.w * lw0.w;
      acc[i][1] += sv.x * lw1.x + sv.y * lw1.y + sv.z * lw1.z + sv.w * lw1.w;
    }
  }
#pragma unroll
  for (int i = 0; i < 4; ++i) {
    int d = dchunk * 32 + dy * 4 + i;
    M1T[((size_t)b * D2 + ox) * D1 + d]        = f2bf(acc[i][0] * inv);
    M1T[((size_t)b * D2 + ox + 32) * D1 + d]   = f2bf(acc[i][1] * inv);
    if (b == 0) {
      R1T[ox * D1 + d]        = f2bf(c1_rw[ox * D1 + d]        - lw_s[ox][d] * inv);
      R1T[(ox + 32) * D1 + d] = f2bf(c1_rw[(ox + 32) * D1 + d] - lw_s[ox + 32][d] * inv);
    }
  }
}

// ---------------- K4: h1 = relu([xn | nrm*xn] @ [M1T|R1T]^T + c1_lb) (K=256 MFMA) ------
__global__ __launch_bounds__(256) void k_h1(const USH* __restrict__ xnb,
                                            const float* __restrict__ nrm,
                                            const USH* __restrict__ M1T,
                                            const USH* __restrict__ R1T,
                                            const float* __restrict__ c1_lb,
                                            USH* __restrict__ h1b,
                                            USH* __restrict__ h1bT) {
  __shared__ __align__(16) short TA[64][280];
  __shared__ __align__(16) short TB[64][280];
  __shared__ __align__(16) USH  T2[64][72];
  const int t = threadIdx.x;
  const int row0 = blockIdx.x * 64;
  const int b = row0 >> 11, nloc = row0 & (NN - 1);
  {
    const int row = t >> 2, seg = t & 3;
    const float nr = nrm[row0 + row];
#pragma unroll
    for (int j = 0; j < 4; ++j) {
      int e = seg * 32 + j * 8;
      short8v v = *reinterpret_cast<const short8v*>(&xnb[(size_t)(row0 + row) * D1 + e]);
      *reinterpret_cast<short8v*>(&TA[row][e]) = v;
      short8v sv;
#pragma unroll
      for (int jj = 0; jj < 8; ++jj) sv[jj] = (short)f2bf(bf2f((USH)v[jj]) * nr);
      *reinterpret_cast<short8v*>(&TA[row][128 + e]) = sv;
      *reinterpret_cast<short8v*>(&TB[row][e]) =
          *reinterpret_cast<const short8v*>(&M1T[((size_t)b * D2 + row) * D1 + e]);
      *reinterpret_cast<short8v*>(&TB[row][128 + e]) =
          *reinterpret_cast<const short8v*>(&R1T[(size_t)row * D1 + e]);
    }
  }
  __syncthreads();
  const int w = t >> 6, l = t & 63;
  const int wm = w & 1, wn = w >> 1;
  f32x4 acc[2][2] = {};
#pragma unroll
  for (int ks = 0; ks < 8; ++ks) {
    short8v a[2], bb[2];
#pragma unroll
    for (int i = 0; i < 2; ++i)
      a[i] = *reinterpret_cast<const short8v*>(&TA[wm * 32 + i * 16 + (l & 15)][ks * 32 + (l >> 4) * 8]);
#pragma unroll
    for (int j = 0; j < 2; ++j)
      bb[j] = *reinterpret_cast<const short8v*>(&TB[wn * 32 + j * 16 + (l & 15)][ks * 32 + (l >> 4) * 8]);
#pragma unroll
    for (int i = 0; i < 2; ++i)
#pragma unroll
      for (int j = 0; j < 2; ++j)
        acc[i][j] = __builtin_amdgcn_mfma_f32_16x16x32_bf16(a[i], bb[j], acc[i][j], 0, 0, 0);
  }
#pragma unroll
  for (int i = 0; i < 2; ++i)
#pragma unroll
    for (int j = 0; j < 2; ++j) {
      int col = wn * 32 + j * 16 + (l & 15);
      float lb = c1_lb[col];
#pragma unroll
      for (int r = 0; r < 4; ++r) {
        int rowL = wm * 32 + i * 16 + (l >> 4) * 4 + r;
        USH hv = f2bf(fmaxf(acc[i][j][r] + lb, 0.0f));
        h1b[(size_t)(row0 + rowL) * D2 + col] = hv;
        T2[col][rowL] = hv;
      }
    }
  __syncthreads();
  {
    int col = t >> 2, seg = t & 3;
    size_t g = ((size_t)b * D2 + col) * NN + nloc + seg * 16;
    *reinterpret_cast<short8v*>(&h1bT[g]) =
        *reinterpret_cast<const short8v*>(&T2[col][seg * 16]);
    *reinterpret_cast<short8v*>(&h1bT[g + 8]) =
        *reinterpret_cast<const short8v*>(&T2[col][seg * 16 + 8]);
  }
}

// ---------------- K5: S2 partials = xnbT(chunk) @ h1bT(chunk)^T via MFMA ----------------
__global__ __launch_bounds__(256) void k_s2(const USH* __restrict__ xnbT,
                                            const USH* __restrict__ h1bT,
                                            float* __restrict__ P2) {
  __shared__ __align__(16) short TA[128][136];
  __shared__ __align__(16) short TB[64][136];
  const int t = threadIdx.x;
  const int ch = blockIdx.x, b = blockIdx.y;
  const int n0 = ch * ROWS_PER_CH;
  {
    const int r0 = t >> 4;
    const int c8 = (t & 15) * 8;
#pragma unroll
    for (int p = 0; p < 8; ++p) {
      int row = p * 16 + r0;
      *reinterpret_cast<short8v*>(&TA[row][c8]) =
          *reinterpret_cast<const short8v*>(&xnbT[((size_t)b * D1 + row) * NN + n0 + c8]);
    }
#pragma unroll
    for (int p = 0; p < 4; ++p) {
      int row = p * 16 + r0;
      *reinterpret_cast<short8v*>(&TB[row][c8]) =
          *reinterpret_cast<const short8v*>(&h1bT[((size_t)b * D2 + row) * NN + n0 + c8]);
    }
  }
  __syncthreads();
  const int w = t >> 6, l = t & 63;
  const int wm = w & 1, wn = w >> 1;
  f32x4 acc[4][2] = {};
#pragma unroll
  for (int ks = 0; ks < 4; ++ks) {
    short8v a[4], bb[2];
#pragma unroll
    for (int fi = 0; fi < 4; ++fi)
      a[fi] = *reinterpret_cast<const short8v*>(&TA[wm * 64 + fi * 16 + (l & 15)][ks * 32 + (l >> 4) * 8]);
#pragma unroll
    for (int fj = 0; fj < 2; ++fj)
      bb[fj] = *reinterpret_cast<const short8v*>(&TB[wn * 32 + fj * 16 + (l & 15)][ks * 32 + (l >> 4) * 8]);
#pragma unroll
    for (int fi = 0; fi < 4; ++fi)
#pragma unroll
      for (int fj = 0; fj < 2; ++fj)
        acc[fi][fj] = __builtin_amdgcn_mfma_f32_16x16x32_bf16(a[fi], bb[fj], acc[fi][fj], 0, 0, 0);
  }
  float* P = P2 + ((size_t)b * NCH + ch) * (D1 * D2);
#pragma unroll
  for (int fi = 0; fi < 4; ++fi)
#pragma unroll
    for (int fj = 0; fj < 2; ++fj)
#pragma unroll
      for (int r = 0; r < 4; ++r) {
        int row = wm * 64 + fi * 16 + (l >> 4) * 4 + r;
        int col = wn * 32 + fj * 16 + (l & 15);
        P[(size_t)row * D2 + col] = acc[fi][fj][r];
      }
}

// ---------------- K6: fused reduce(P2) + m2 = S2@c2_lw/2047 ; r2 (fp32) ----------------
__global__ __launch_bounds__(256) void k_m2_fused(const float* __restrict__ P2,
                                                  const float* __restrict__ c2_lw,
                                                  const float* __restrict__ c2_rw,
                                                  float* __restrict__ m2, float* __restrict__ r2) {
  const int t = threadIdx.x;
  const int dchunk = blockIdx.x, b = blockIdx.y;
  const int dy = t >> 6;
  const int o = t & 63;
  const float inv = 1.0f / 2047.0f;
  const float lw = c2_lw[o];
  const float* Pb = P2 + (size_t)b * NCH * (D1 * D2);
#pragma unroll
  for (int rr = 0; rr < 8; ++rr) {
    int d = dchunk * 32 + dy * 8 + rr;
    const float* p = Pb + (size_t)d * D2 + o;
    float s = 0.f;
#pragma unroll
    for (int c = 0; c < NCH; ++c) s += p[(size_t)c * (D1 * D2)];
    s *= lw;
#pragma unroll
    for (int m = 1; m < 64; m <<= 1) s += __shfl_xor(s, m, 64);
    if (o == 0) m2[b * D1 + d] = s * inv;
  }
  if (b == 0 && dchunk == 0 && t < D2) r2[t] = c2_rw[t] - c2_lw[t] * inv;
}

// ---------------- K7: out = sigmoid(xnb.m2 + h1b.r2 + c2_lb) * mask ----------------
__global__ __launch_bounds__(256) void k_out(const USH* __restrict__ xnb,
                                             const USH* __restrict__ h1b,
                                             const float* __restrict__ m2,
                                             const float* __restrict__ r2,
                                             const float* __restrict__ c2_lb,
                                             const float* __restrict__ mask,
                                             float* __restrict__ out) {
  int row = blockIdx.x * 4 + (threadIdx.x >> 6);
  int lane = threadIdx.x & 63;
  int b = row >> 11;
  float s = bf2f(xnb[(size_t)row * D1 + lane]) * m2[b * D1 + lane]
          + bf2f(xnb[(size_t)row * D1 + 64 + lane]) * m2[b * D1 + 64 + lane]
          + bf2f(h1b[(size_t)row * D2 + lane]) * r2[lane];
#pragma unroll
  for (int m = 1; m < 64; m <<= 1) s += __shfl_xor(s, m, 64);
  if (lane == 0) {
    float v = s + c2_lb[0];
    out[row] = (1.0f / (1.0f + expf(-v))) * mask[row];
  }
}

extern "C" void kernel_launch(void* const* d_in, const int* in_sizes, int n_in,
                              void* d_out, int out_size, void* d_ws, size_t ws_size,
                              hipStream_t stream) {
  const float* x      = (const float*)d_in[0];
  const float* mask   = (const float*)d_in[1];
  const float* w1     = (const float*)d_in[2];
  const float* b1     = (const float*)d_in[3];
  const float* c1_lw  = (const float*)d_in[4];
  const float* c1_lb  = (const float*)d_in[5];
  const float* c1_rw  = (const float*)d_in[6];
  const float* c2_lw  = (const float*)d_in[7];
  const float* c2_lb  = (const float*)d_in[8];
  const float* c2_rw  = (const float*)d_in[9];
  float* ws  = (float*)d_ws;
  USH* xnb   = (USH*)(ws + OFF_XNB);
  USH* xnbT  = (USH*)(ws + OFF_XNBT);
  float* nrm = ws + OFF_NRM;
  USH* h1b   = (USH*)(ws + OFF_H1B);
  USH* h1bT  = (USH*)(ws + OFF_H1BT);
  float* P1  = ws + OFF_P1;
  float* P2  = ws + OFF_P2;
  USH* M1T   = (USH*)(ws + OFF_M1T);
  USH* R1T   = (USH*)(ws + OFF_R1T);
  float* m2  = ws + OFF_M2;
  float* r2  = ws + OFF_R2;
  USH* w1b   = (USH*)(ws + OFF_P1);  // aliases P1 (P1 written only after gemm_h done)
  float* out = (float*)d_out;

  k_cvt_w1<<<dim3((D1 * HH) / 1024), dim3(256), 0, stream>>>(w1, w1b);
  k_gemm_h<<<dim3(BN / 32), dim3(256), 0, stream>>>(x, w1b, b1, xnb, xnbT, nrm);
  k_s1<<<dim3(NCH, BB), dim3(256), 0, stream>>>(xnbT, nrm, P1);
  k_m1_fused<<<dim3(4, BB), dim3(256), 0, stream>>>(P1, c1_lw, c1_rw, M1T, R1T);
  k_h1<<<dim3(BN / 64), dim3(256), 0, stream>>>(xnb, nrm, M1T, R1T, c1_lb, h1b, h1bT);
  k_s2<<<dim3(NCH, BB), dim3(256), 0, stream>>>(xnbT, h1bT, P2);
  k_m2_fused<<<dim3(4, BB), dim3(256), 0, stream>>>(P2, c2_lw, c2_rw, m2, r2);
  k_out<<<dim3(BN / 4), dim3(256), 0, stream>>>(xnb, h1b, m2, r2, c2_lb, mask, out);
}

// Round 6
// 48.707 us; speedup vs baseline: 3.6762x; 1.2446x over previous
//
#include <hip/hip_runtime.h>
#include <hip/hip_bf16.h>
#include <math.h>

#define BB 8
#define NN 2048
#define HH 768
#define D1 128
#define D2 64
#define BN (BB*NN)            // 16384 rows total
#define NCH 16                // split-n chunks for S1 partial reduction
#define ROWS_PER_CH (NN/NCH)  // 128

// workspace offsets (floats)
#define OFF_XNB   0u          // bf16 [BN][128]
#define OFF_XNBT  1048576u    // bf16 [8][128][2048]
#define OFF_NRM   2097152u    // f32  [BN]
#define OFF_W2    2113536u    // f32  [BN]   (h1 . c2_lw per row)
#define OFF_T2V   2129920u    // f32  [BN]   (h1 . r2 per row)
#define OFF_P1    2146304u    // f32 [8][16][128][128]  (w1b bf16 aliases here pre-s1)
#define OFF_M1T   4243456u    // bf16 [8][64][128]
#define OFF_R1T   4276224u    // bf16 [64][128]
#define OFF_M2F   4280320u    // f32 [8][128]
#define OFF_R2F   4281344u    // f32 [64]

typedef __attribute__((ext_vector_type(8))) short short8v;
typedef __attribute__((ext_vector_type(4))) float f32x4;
typedef unsigned short USH;

__device__ __forceinline__ USH f2bf(float f) {
  unsigned int u = __builtin_bit_cast(unsigned int, f);
  u = (u + 0x7fffu + ((u >> 16) & 1u)) >> 16;
  return (USH)u;
}
__device__ __forceinline__ float bf2f(USH u) {
  return __builtin_bit_cast(float, ((unsigned int)u) << 16);
}

#define GLDS16(gp, lp)                                                        \
  __builtin_amdgcn_global_load_lds((const __attribute__((address_space(1))) void*)(gp), \
                                   (__attribute__((address_space(3))) void*)(lp), 16, 0, 0)

// ---------------- K0: prep — w1->bf16, R1T = (c1_rw - c1_lw/2047)^T-ish, r2 ----------------
// R1T[o][d] = c1_rw[o][d] - c1_lw[o][d]/2047 (linear elementwise over [64][128])
__global__ __launch_bounds__(256) void k_prep(const float* __restrict__ w1,
                                              const float* __restrict__ c1_lw,
                                              const float* __restrict__ c1_rw,
                                              const float* __restrict__ c2_lw,
                                              const float* __restrict__ c2_rw,
                                              USH* __restrict__ w1b,
                                              USH* __restrict__ R1T,
                                              float* __restrict__ r2f) {
  const int bid = blockIdx.x, t = threadIdx.x;
  const float inv = 1.0f / 2047.0f;
  if (bid < 96) {
    int i = (bid * 256 + t) * 4;
    float4 v = *reinterpret_cast<const float4*>(&w1[i]);
    ushort4 o;
    o.x = f2bf(v.x); o.y = f2bf(v.y); o.z = f2bf(v.z); o.w = f2bf(v.w);
    *reinterpret_cast<ushort4*>(&w1b[i]) = o;
  } else if (bid < 98) {
    int base = (bid - 96) * 4096 + t * 16;
#pragma unroll
    for (int k = 0; k < 16; ++k) {
      int i = base + k;
      R1T[i] = f2bf(c1_rw[i] - c1_lw[i] * inv);
    }
  } else {
    if (t < D2) r2f[t] = c2_rw[t] - c2_lw[t] * inv;
  }
}

// ---------------- K1: h = x @ w1^T + b1 (bf16 MFMA, BM=32 BK=64, swizzled LDS) --------
// emits xnb [n][128], xnbT [b][128][2048], nrm [n]   (h == xn * nrm, never stored)
__global__ __launch_bounds__(256) void k_gemm_h(const float* __restrict__ x,
                                                const USH* __restrict__ w1b,
                                                const float* __restrict__ b1,
                                                USH* __restrict__ xnb,
                                                USH* __restrict__ xnbT,
                                                float* __restrict__ nrm) {
  __shared__ __align__(16) USH As[2][32][64];   // 8 KB  (slot-swizzled)
  __shared__ __align__(16) USH Bs[2][128][64];  // 32 KB (slot-swizzled)
  __shared__ float norms[32][2];
  __shared__ __align__(16) USH T[128][40];      // 10 KB transpose buffer

  const int t = threadIdx.x;
  const int w = t >> 6, l = t & 63;
  const int wm = w & 1, wn = w >> 1;
  const int row0 = blockIdx.x * 32;
  const int b_ = row0 >> 11, nloc = row0 & (NN - 1);

  const int arow = t >> 3, aseg = t & 7;
  const int aslot = aseg ^ (arow & 7);
  const size_t xbase = (size_t)(row0 + arow) * HH;
  const int brow_l = w * 32 + (l >> 3);

  f32x4 acc[4] = {};

  {  // prologue: buffer 0
#pragma unroll
    for (int q = 0; q < 4; ++q) {
      int brow = brow_l + q * 8;
      int gslot = (l & 7) ^ (brow & 7);
      GLDS16(w1b + (size_t)brow * HH + gslot * 8, &Bs[0][w * 32 + q * 8][0]);
    }
    float4 xa = *reinterpret_cast<const float4*>(&x[xbase + aseg * 8]);
    float4 xb = *reinterpret_cast<const float4*>(&x[xbase + aseg * 8 + 4]);
    short8v v;
    v[0] = (short)f2bf(xa.x); v[1] = (short)f2bf(xa.y);
    v[2] = (short)f2bf(xa.z); v[3] = (short)f2bf(xa.w);
    v[4] = (short)f2bf(xb.x); v[5] = (short)f2bf(xb.y);
    v[6] = (short)f2bf(xb.z); v[7] = (short)f2bf(xb.w);
    *reinterpret_cast<short8v*>(&As[0][arow][aslot * 8]) = v;
  }

  for (int kt = 0; kt < HH / 64; ++kt) {
    const int cur = kt & 1, nxt = cur ^ 1;
    __syncthreads();

    float4 xa, xb;
    if (kt < HH / 64 - 1) {
      const int k0n = (kt + 1) * 64;
#pragma unroll
      for (int q = 0; q < 4; ++q) {
        int brow = brow_l + q * 8;
        int gslot = (l & 7) ^ (brow & 7);
        GLDS16(w1b + (size_t)brow * HH + k0n + gslot * 8, &Bs[nxt][w * 32 + q * 8][0]);
      }
      xa = *reinterpret_cast<const float4*>(&x[xbase + k0n + aseg * 8]);
      xb = *reinterpret_cast<const float4*>(&x[xbase + k0n + aseg * 8 + 4]);
    }

    const int ar = wm * 16 + (l & 15);
#pragma unroll
    for (int ks = 0; ks < 2; ++ks) {
      short8v a = *reinterpret_cast<const short8v*>(
          &As[cur][ar][((ks * 4 + (l >> 4)) ^ (ar & 7)) * 8]);
#pragma unroll
      for (int ni = 0; ni < 4; ++ni) {
        int br = wn * 64 + ni * 16 + (l & 15);
        short8v b = *reinterpret_cast<const short8v*>(
            &Bs[cur][br][((ks * 4 + (l >> 4)) ^ (br & 7)) * 8]);
        acc[ni] = __builtin_amdgcn_mfma_f32_16x16x32_bf16(a, b, acc[ni], 0, 0, 0);
      }
    }

    if (kt < HH / 64 - 1) {
      short8v v;
      v[0] = (short)f2bf(xa.x); v[1] = (short)f2bf(xa.y);
      v[2] = (short)f2bf(xa.z); v[3] = (short)f2bf(xa.w);
      v[4] = (short)f2bf(xb.x); v[5] = (short)f2bf(xb.y);
      v[6] = (short)f2bf(xb.z); v[7] = (short)f2bf(xb.w);
      *reinterpret_cast<short8v*>(&As[nxt][arow][aslot * 8]) = v;
    }
  }

  // epilogue: bias, row-norm, write xnb + xnbT + nrm
  float bv[4];
#pragma unroll
  for (int ni = 0; ni < 4; ++ni) bv[ni] = b1[wn * 64 + ni * 16 + (l & 15)];
#pragma unroll
  for (int ni = 0; ni < 4; ++ni)
#pragma unroll
    for (int r = 0; r < 4; ++r) acc[ni][r] += bv[ni];

#pragma unroll
  for (int r = 0; r < 4; ++r) {
    float s = 0.f;
#pragma unroll
    for (int ni = 0; ni < 4; ++ni) { float v = acc[ni][r]; s += v * v; }
#pragma unroll
    for (int m = 1; m < 16; m <<= 1) s += __shfl_xor(s, m, 64);
    if ((l & 15) == 0) norms[wm * 16 + (l >> 4) * 4 + r][wn] = s;
  }
  __syncthreads();

#pragma unroll
  for (int r = 0; r < 4; ++r) {
    int row = wm * 16 + (l >> 4) * 4 + r;
    float tot = norms[row][0] + norms[row][1];
    float ncl = fmaxf(sqrtf(tot), 1e-8f);
    float inv = 1.0f / ncl;
    if (wn == 0 && (l & 15) == 0) nrm[row0 + row] = ncl;
    size_t gbase = (size_t)(row0 + row) * D1;
#pragma unroll
    for (int ni = 0; ni < 4; ++ni) {
      int col = wn * 64 + ni * 16 + (l & 15);
      USH xv = f2bf(acc[ni][r] * inv);
      xnb[gbase + col] = xv;
      T[col][row] = xv;
    }
  }
  __syncthreads();
  {
    int d = t >> 1, seg = t & 1;
    size_t g = ((size_t)b_ * D1 + d) * NN + nloc + seg * 16;
    *reinterpret_cast<short8v*>(&xnbT[g]) =
        *reinterpret_cast<const short8v*>(&T[d][seg * 16]);
    *reinterpret_cast<short8v*>(&xnbT[g + 8]) =
        *reinterpret_cast<const short8v*>(&T[d][seg * 16 + 8]);
  }
}

// ---------------- K2: S1 partials = xnT(chunk) @ (diag(nrm) xn)(chunk) via MFMA --------
__global__ __launch_bounds__(256) void k_s1(const USH* __restrict__ xnbT,
                                            const float* __restrict__ nrm,
                                            float* __restrict__ P1) {
  __shared__ __align__(16) short TA[128][136];
  __shared__ __align__(16) short TB[128][136];
  const int t = threadIdx.x;
  const int ch = blockIdx.x, b = blockIdx.y;
  const int n0 = ch * ROWS_PER_CH;
  {
    const int r0 = t >> 4;
    const int c8 = (t & 15) * 8;
    float4 nva = *reinterpret_cast<const float4*>(&nrm[(size_t)b * NN + n0 + c8]);
    float4 nvb = *reinterpret_cast<const float4*>(&nrm[(size_t)b * NN + n0 + c8 + 4]);
    float nv[8] = {nva.x, nva.y, nva.z, nva.w, nvb.x, nvb.y, nvb.z, nvb.w};
#pragma unroll
    for (int p = 0; p < 8; ++p) {
      int row = p * 16 + r0;
      short8v v = *reinterpret_cast<const short8v*>(&xnbT[((size_t)b * D1 + row) * NN + n0 + c8]);
      *reinterpret_cast<short8v*>(&TA[row][c8]) = v;
      short8v hv;
#pragma unroll
      for (int j = 0; j < 8; ++j) hv[j] = (short)f2bf(bf2f((USH)v[j]) * nv[j]);
      *reinterpret_cast<short8v*>(&TB[row][c8]) = hv;
    }
  }
  __syncthreads();
  const int w = t >> 6, l = t & 63;
  const int wm = w & 1, wn = w >> 1;
  f32x4 acc[4][4] = {};
#pragma unroll
  for (int ks = 0; ks < 4; ++ks) {
    short8v a[4], bb[4];
#pragma unroll
    for (int fi = 0; fi < 4; ++fi)
      a[fi] = *reinterpret_cast<const short8v*>(&TA[wm * 64 + fi * 16 + (l & 15)][ks * 32 + (l >> 4) * 8]);
#pragma unroll
    for (int fj = 0; fj < 4; ++fj)
      bb[fj] = *reinterpret_cast<const short8v*>(&TB[wn * 64 + fj * 16 + (l & 15)][ks * 32 + (l >> 4) * 8]);
#pragma unroll
    for (int fi = 0; fi < 4; ++fi)
#pragma unroll
      for (int fj = 0; fj < 4; ++fj)
        acc[fi][fj] = __builtin_amdgcn_mfma_f32_16x16x32_bf16(a[fi], bb[fj], acc[fi][fj], 0, 0, 0);
  }
  float* P = P1 + ((size_t)b * NCH + ch) * (D1 * D1);
#pragma unroll
  for (int fi = 0; fi < 4; ++fi)
#pragma unroll
    for (int fj = 0; fj < 4; ++fj)
#pragma unroll
      for (int r = 0; r < 4; ++r) {
        int row = wm * 64 + fi * 16 + (l >> 4) * 4 + r;
        int col = wn * 64 + fj * 16 + (l & 15);
        P[(size_t)row * D1 + col] = acc[fi][fj][r];
      }
}

// ---------------- K3: fused reduce(P1) + M1T = (S1@c1_lw^T/2047)^T (bf16) --------------
// grid (16 d-chunks of 8 rows, 8 b), 256 threads
__global__ __launch_bounds__(256) void k_m1_fused(const float* __restrict__ P1,
                                                  const float* __restrict__ c1_lw,
                                                  USH* __restrict__ M1T) {
  __shared__ float s_s[8][128];     // 4 KB
  __shared__ float lw_s[64][132];   // 33.8 KB
  const int t = threadIdx.x;
  const int dchunk = blockIdx.x;    // rows dchunk*8 .. +7
  const int b = blockIdx.y;
  const float inv = 1.0f / 2047.0f;

#pragma unroll
  for (int q = 0; q < 8; ++q) {
    int idx4 = q * 256 + t;
    int o = idx4 >> 5, e4 = idx4 & 31;
    float4 v = *reinterpret_cast<const float4*>(&c1_lw[o * 128 + e4 * 4]);
    *reinterpret_cast<float4*>(&lw_s[o][e4 * 4]) = v;
  }
  const float* Pb = P1 + (size_t)b * NCH * (D1 * D1) + (size_t)(dchunk * 8) * D1;
  {
    int r = t >> 5, e4 = t & 31;
    float4 s = make_float4(0.f, 0.f, 0.f, 0.f);
#pragma unroll
    for (int c = 0; c < NCH; ++c) {
      float4 v = *reinterpret_cast<const float4*>(&Pb[(size_t)c * (D1 * D1) + r * D1 + e4 * 4]);
      s.x += v.x; s.y += v.y; s.z += v.z; s.w += v.w;
    }
    *reinterpret_cast<float4*>(&s_s[r][e4 * 4]) = s;
  }
  __syncthreads();

  const int row = t >> 5;           // 0..7
  const int ox = t & 31;            // o and o+32
  float a0 = 0.f, a1 = 0.f;
  for (int e4 = 0; e4 < 32; ++e4) {
    float4 lw0 = *reinterpret_cast<const float4*>(&lw_s[ox][e4 * 4]);
    float4 lw1 = *reinterpret_cast<const float4*>(&lw_s[ox + 32][e4 * 4]);
    float4 sv = *reinterpret_cast<const float4*>(&s_s[row][e4 * 4]);
    a0 += sv.x * lw0.x + sv.y * lw0.y + sv.z * lw0.z + sv.w * lw0.w;
    a1 += sv.x * lw1.x + sv.y * lw1.y + sv.z * lw1.z + sv.w * lw1.w;
  }
  int d = dchunk * 8 + row;
  M1T[((size_t)b * D2 + ox) * D1 + d]      = f2bf(a0 * inv);
  M1T[((size_t)b * D2 + ox + 32) * D1 + d] = f2bf(a1 * inv);
}

// ---------------- K4: h1 = relu([xn | nrm*xn] @ [M1T|R1T]^T + c1_lb) (K=256 MFMA) ------
// epilogue reduces h1 rows against c2_lw and r2 -> w2[n], t2[n] (fp32). No h1 stored.
__global__ __launch_bounds__(256) void k_h1(const USH* __restrict__ xnb,
                                            const float* __restrict__ nrm,
                                            const USH* __restrict__ M1T,
                                            const USH* __restrict__ R1T,
                                            const float* __restrict__ c1_lb,
                                            const float* __restrict__ c2_lw,
                                            const float* __restrict__ r2f,
                                            float* __restrict__ w2,
                                            float* __restrict__ t2v) {
  __shared__ __align__(16) short TA[64][280];
  __shared__ __align__(16) short TB[64][280];
  __shared__ float ws2[64][2], ts2[64][2];
  const int t = threadIdx.x;
  const int row0 = blockIdx.x * 64;
  const int b = row0 >> 11;
  {
    const int row = t >> 2, seg = t & 3;
    const float nr = nrm[row0 + row];
#pragma unroll
    for (int j = 0; j < 4; ++j) {
      int e = seg * 32 + j * 8;
      short8v v = *reinterpret_cast<const short8v*>(&xnb[(size_t)(row0 + row) * D1 + e]);
      *reinterpret_cast<short8v*>(&TA[row][e]) = v;
      short8v sv;
#pragma unroll
      for (int jj = 0; jj < 8; ++jj) sv[jj] = (short)f2bf(bf2f((USH)v[jj]) * nr);
      *reinterpret_cast<short8v*>(&TA[row][128 + e]) = sv;
      *reinterpret_cast<short8v*>(&TB[row][e]) =
          *reinterpret_cast<const short8v*>(&M1T[((size_t)b * D2 + row) * D1 + e]);
      *reinterpret_cast<short8v*>(&TB[row][128 + e]) =
          *reinterpret_cast<const short8v*>(&R1T[(size_t)row * D1 + e]);
    }
  }
  __syncthreads();
  const int w = t >> 6, l = t & 63;
  const int wm = w & 1, wn = w >> 1;
  f32x4 acc[2][2] = {};
#pragma unroll
  for (int ks = 0; ks < 8; ++ks) {
    short8v a[2], bb[2];
#pragma unroll
    for (int i = 0; i < 2; ++i)
      a[i] = *reinterpret_cast<const short8v*>(&TA[wm * 32 + i * 16 + (l & 15)][ks * 32 + (l >> 4) * 8]);
#pragma unroll
    for (int j = 0; j < 2; ++j)
      bb[j] = *reinterpret_cast<const short8v*>(&TB[wn * 32 + j * 16 + (l & 15)][ks * 32 + (l >> 4) * 8]);
#pragma unroll
    for (int i = 0; i < 2; ++i)
#pragma unroll
      for (int j = 0; j < 2; ++j)
        acc[i][j] = __builtin_amdgcn_mfma_f32_16x16x32_bf16(a[i], bb[j], acc[i][j], 0, 0, 0);
  }
  // per-row reductions against c2_lw and r2
  float cw[2], rv[2], lb[2];
#pragma unroll
  for (int j = 0; j < 2; ++j) {
    int col = wn * 32 + j * 16 + (l & 15);
    cw[j] = c2_lw[col]; rv[j] = r2f[col]; lb[j] = c1_lb[col];
  }
#pragma unroll
  for (int i = 0; i < 2; ++i)
#pragma unroll
    for (int r = 0; r < 4; ++r) {
      float wp = 0.f, tp = 0.f;
#pragma unroll
      for (int j = 0; j < 2; ++j) {
        float val = fmaxf(acc[i][j][r] + lb[j], 0.0f);
        wp += val * cw[j];
        tp += val * rv[j];
      }
#pragma unroll
      for (int m = 1; m < 16; m <<= 1) {
        wp += __shfl_xor(wp, m, 64);
        tp += __shfl_xor(tp, m, 64);
      }
      if ((l & 15) == 0) {
        int rowL = wm * 32 + i * 16 + (l >> 4) * 4 + r;
        ws2[rowL][wn] = wp;
        ts2[rowL][wn] = tp;
      }
    }
  __syncthreads();
  if (t < 64) {
    w2[row0 + t]  = ws2[t][0] + ws2[t][1];
    t2v[row0 + t] = ts2[t][0] + ts2[t][1];
  }
}

// ---------------- K5: m2[b][d] = (sum_n xnbT[b][d][n] * w2[b][n]) / 2047 (GEMV) --------
// grid (32, 8), 4 waves; wave handles one d-row
__global__ __launch_bounds__(256) void k_m2(const USH* __restrict__ xnbT,
                                            const float* __restrict__ w2,
                                            float* __restrict__ m2f) {
  const int t = threadIdx.x;
  const int w = t >> 6, l = t & 63;
  const int b = blockIdx.y;
  const int d = blockIdx.x * 4 + w;
  const USH* xr = xnbT + ((size_t)b * D1 + d) * NN;
  const float* wr = w2 + (size_t)b * NN;
  float s = 0.f;
#pragma unroll
  for (int pass = 0; pass < 4; ++pass) {
    int n0 = pass * 512 + l * 8;
    short8v xv = *reinterpret_cast<const short8v*>(&xr[n0]);
    float4 wa = *reinterpret_cast<const float4*>(&wr[n0]);
    float4 wb = *reinterpret_cast<const float4*>(&wr[n0 + 4]);
    s += bf2f((USH)xv[0]) * wa.x + bf2f((USH)xv[1]) * wa.y
       + bf2f((USH)xv[2]) * wa.z + bf2f((USH)xv[3]) * wa.w
       + bf2f((USH)xv[4]) * wb.x + bf2f((USH)xv[5]) * wb.y
       + bf2f((USH)xv[6]) * wb.z + bf2f((USH)xv[7]) * wb.w;
  }
#pragma unroll
  for (int m = 1; m < 64; m <<= 1) s += __shfl_xor(s, m, 64);
  if (l == 0) m2f[b * D1 + d] = s * (1.0f / 2047.0f);
}

// ---------------- K6: out = sigmoid(xnb.m2 + t2 + c2_lb) * mask ----------------
__global__ __launch_bounds__(256) void k_out(const USH* __restrict__ xnb,
                                             const float* __restrict__ m2f,
                                             const float* __restrict__ t2v,
                                             const float* __restrict__ c2_lb,
                                             const float* __restrict__ mask,
                                             float* __restrict__ out) {
  int row = blockIdx.x * 4 + (threadIdx.x >> 6);
  int lane = threadIdx.x & 63;
  int b = row >> 11;
  float s = bf2f(xnb[(size_t)row * D1 + lane]) * m2f[b * D1 + lane]
          + bf2f(xnb[(size_t)row * D1 + 64 + lane]) * m2f[b * D1 + 64 + lane];
#pragma unroll
  for (int m = 1; m < 64; m <<= 1) s += __shfl_xor(s, m, 64);
  if (lane == 0) {
    float v = s + t2v[row] + c2_lb[0];
    out[row] = (1.0f / (1.0f + expf(-v))) * mask[row];
  }
}

extern "C" void kernel_launch(void* const* d_in, const int* in_sizes, int n_in,
                              void* d_out, int out_size, void* d_ws, size_t ws_size,
                              hipStream_t stream) {
  const float* x      = (const float*)d_in[0];
  const float* mask   = (const float*)d_in[1];
  const float* w1     = (const float*)d_in[2];
  const float* b1     = (const float*)d_in[3];
  const float* c1_lw  = (const float*)d_in[4];
  const float* c1_lb  = (const float*)d_in[5];
  const float* c1_rw  = (const float*)d_in[6];
  const float* c2_lw  = (const float*)d_in[7];
  const float* c2_lb  = (const float*)d_in[8];
  const float* c2_rw  = (const float*)d_in[9];
  float* ws  = (float*)d_ws;
  USH* xnb   = (USH*)(ws + OFF_XNB);
  USH* xnbT  = (USH*)(ws + OFF_XNBT);
  float* nrm = ws + OFF_NRM;
  float* w2  = ws + OFF_W2;
  float* t2v = ws + OFF_T2V;
  float* P1  = ws + OFF_P1;
  USH* M1T   = (USH*)(ws + OFF_M1T);
  USH* R1T   = (USH*)(ws + OFF_R1T);
  float* m2f = ws + OFF_M2F;
  float* r2f = ws + OFF_R2F;
  USH* w1b   = (USH*)(ws + OFF_P1);  // aliases P1 (P1 written only after gemm_h done)
  float* out = (float*)d_out;

  k_prep<<<dim3(99), dim3(256), 0, stream>>>(w1, c1_lw, c1_rw, c2_lw, c2_rw, w1b, R1T, r2f);
  k_gemm_h<<<dim3(BN / 32), dim3(256), 0, stream>>>(x, w1b, b1, xnb, xnbT, nrm);
  k_s1<<<dim3(NCH, BB), dim3(256), 0, stream>>>(xnbT, nrm, P1);
  k_m1_fused<<<dim3(16, BB), dim3(256), 0, stream>>>(P1, c1_lw, M1T);
  k_h1<<<dim3(BN / 64), dim3(256), 0, stream>>>(xnb, nrm, M1T, R1T, c1_lb, c2_lw, r2f, w2, t2v);
  k_m2<<<dim3(32, BB), dim3(256), 0, stream>>>(xnbT, w2, m2f);
  k_out<<<dim3(BN / 4), dim3(256), 0, stream>>>(xnb, m2f, t2v, c2_lb, mask, out);
}